// Round 3
// baseline (8562.709 us; speedup 1.0000x reference)
//
#include <hip/hip_runtime.h>
#include <hip/hip_bf16.h>

#define NN 115200      // nodes
#define NE 921600      // edges
#define NG 512         // graphs
#define EPSV 1e-5f

typedef unsigned short u16;
struct __align__(8) US4 { u16 x, y, z, w; };

static __device__ __forceinline__ float bf(u16 u) {
    return __uint_as_float(((unsigned)u) << 16);
}
static __device__ __forceinline__ u16 fb(float f) {
    unsigned u = __float_as_uint(f);
    return (u16)((u + 0x7FFFu + ((u >> 16) & 1u)) >> 16);   // RNE
}

// ---------- layer-1: agg0[d] += vert[s] ----------
__global__ void k_edge_s0(const int* __restrict__ ei, const float* __restrict__ vert,
                          float* __restrict__ agg0) {
    const int e = blockIdx.x * 256 + threadIdx.x;
    if (e < NE) atomicAdd(&agg0[ei[NE + e]], vert[ei[e]]);
}

// ---------- W1/b1 closed-form LN stats + per-feature vectors ----------
// X[r,j] = relu(u_r*Wg[j] + w_r*Bg[j] + Bt[j]),  u=s0*rs, w=rs
__global__ void k_prep(const float* __restrict__ W1, const float* __restrict__ b1,
                       const float* __restrict__ lng, const float* __restrict__ lnb,
                       float* __restrict__ Wg, float* __restrict__ Bg,
                       float* __restrict__ Bt, float* __restrict__ stat) {
    const int j = threadIdx.x;
    const float w = W1[j], b = b1[j];
    __shared__ float r1[256], r2[256], r3[256];
    r1[j] = w; r2[j] = b; __syncthreads();
    for (int o = 128; o > 0; o >>= 1) {
        if (j < o) { r1[j] += r1[j + o]; r2[j] += r2[j + o]; }
        __syncthreads();
    }
    const float mW = r1[0] * (1.f / 256.f), mB = r2[0] * (1.f / 256.f);
    __syncthreads();
    const float dw = w - mW, db = b - mB;
    r1[j] = dw * dw; r2[j] = db * db; r3[j] = dw * db; __syncthreads();
    for (int o = 128; o > 0; o >>= 1) {
        if (j < o) { r1[j] += r1[j + o]; r2[j] += r2[j + o]; r3[j] += r3[j + o]; }
        __syncthreads();
    }
    if (j == 0) { stat[0] = r1[0] * (1.f / 256.f); stat[1] = r3[0] * (1.f / 256.f);
                  stat[2] = r2[0] * (1.f / 256.f); }
    const float gj = lng[j];
    Wg[j] = dw * gj; Bg[j] = db * gj; Bt[j] = lnb[j];
}

// ---------- per-node u,w scalars ----------
__global__ void k_uw(const float* __restrict__ vert, const float* __restrict__ agg0,
                     const float* __restrict__ stat, float2* __restrict__ UW) {
    const int r = blockIdx.x * 256 + threadIdx.x;
    const float s0 = vert[r] + agg0[r];
    const float var = s0 * s0 * stat[0] + 2.f * s0 * stat[1] + stat[2];
    const float rs = rsqrtf(var + EPSV);
    UW[r] = make_float2(s0 * rs, rs);
}

// ---------- layer-2 aggregation: S[d,:] += X(s,:) on the fly ----------
__global__ void k_aggX(const int* __restrict__ ei, const float2* __restrict__ UW,
                       const float* __restrict__ Wg, const float* __restrict__ Bg,
                       const float* __restrict__ Bt, float* __restrict__ S) {
    __shared__ float sWg[256], sBg[256], sBt[256];
    const int tid = threadIdx.x;
    sWg[tid] = Wg[tid]; sBg[tid] = Bg[tid]; sBt[tid] = Bt[tid];
    __syncthreads();
    const int sub = tid >> 6, lane = tid & 63, j = lane * 4;
    for (int e = blockIdx.x * 4 + sub; e < NE; e += gridDim.x * 4) {
        const int s = ei[e], d = ei[NE + e];
        const float2 uw = UW[s];
        float* dp = S + (size_t)d * 256 + j;
        atomicAdd(dp + 0, fmaxf(uw.x * sWg[j + 0] + uw.y * sBg[j + 0] + sBt[j + 0], 0.f));
        atomicAdd(dp + 1, fmaxf(uw.x * sWg[j + 1] + uw.y * sBg[j + 1] + sBt[j + 1], 0.f));
        atomicAdd(dp + 2, fmaxf(uw.x * sWg[j + 2] + uw.y * sBg[j + 2] + sBt[j + 2], 0.f));
        atomicAdd(dp + 3, fmaxf(uw.x * sWg[j + 3] + uw.y * sBg[j + 3] + sBt[j + 3], 0.f));
    }
}

// ---------- layer-3 aggregation: S[d,:] += Y[s,:] (bf16 matrix) ----------
__global__ void k_aggY(const int* __restrict__ ei, const u16* __restrict__ Y,
                       float* __restrict__ S) {
    const int idx = blockIdx.x * 256 + threadIdx.x;
    const int e = idx >> 6, lane = idx & 63;
    const int s = ei[e], d = ei[NE + e];
    const US4 u = *(const US4*)(Y + (size_t)s * 256 + lane * 4);
    float* dp = S + (size_t)d * 256 + lane * 4;
    atomicAdd(dp + 0, bf(u.x));
    atomicAdd(dp + 1, bf(u.y));
    atomicAdd(dp + 2, bf(u.z));
    atomicAdd(dp + 3, bf(u.w));
}

// ---------- GIN GEMM with fused LayerNorm+ReLU epilogue ----------
// OUT = relu(LN((A + S) @ W + bias)), A = X_otf (SRC=0) or bf16 Ab (SRC=1)
// tile: 64 rows x 256 cols (full row per block), 256 threads, 8x8 acc
template<int SRC>
__global__ __launch_bounds__(256) void k_gemm_ln(
    const float2* __restrict__ UW, const float* __restrict__ Wg,
    const float* __restrict__ Bg, const float* __restrict__ Bt,
    const u16* __restrict__ Ab, const float* __restrict__ S,
    const float* __restrict__ W, const float* __restrict__ bias,
    const float* __restrict__ g, const float* __restrict__ b,
    u16* __restrict__ OUT) {
    __shared__ float As[32][68];    // [k][row], row-stride 272B
    __shared__ float Bs[32][256];   // [k][col]
    __shared__ float mu_s[64], rs_s[64];
    const int tid = threadIdx.x;
    const int brow = blockIdx.x * 64;
    const int tr = tid >> 5, tc = tid & 31;   // 8 x 32 threads -> rows 8x8, cols 32x8
    float acc[8][8] = {};
    for (int k0 = 0; k0 < 256; k0 += 32) {
        {   // A stage: 64 rows x 32 k
            const int f = tid & 7, r0 = tid >> 3;
            #pragma unroll
            for (int p = 0; p < 2; p++) {
                const int r = r0 + p * 32;
                const float4 sv = *(const float4*)&S[(size_t)(brow + r) * 256 + k0 + f * 4];
                float x0, x1, x2, x3;
                if (SRC == 0) {
                    const float2 uw = UW[brow + r];
                    const int kb = k0 + f * 4;
                    x0 = fmaxf(uw.x * Wg[kb + 0] + uw.y * Bg[kb + 0] + Bt[kb + 0], 0.f);
                    x1 = fmaxf(uw.x * Wg[kb + 1] + uw.y * Bg[kb + 1] + Bt[kb + 1], 0.f);
                    x2 = fmaxf(uw.x * Wg[kb + 2] + uw.y * Bg[kb + 2] + Bt[kb + 2], 0.f);
                    x3 = fmaxf(uw.x * Wg[kb + 3] + uw.y * Bg[kb + 3] + Bt[kb + 3], 0.f);
                } else {
                    const US4 ua = *(const US4*)(Ab + (size_t)(brow + r) * 256 + k0 + f * 4);
                    x0 = bf(ua.x); x1 = bf(ua.y); x2 = bf(ua.z); x3 = bf(ua.w);
                }
                As[f * 4 + 0][r] = x0 + sv.x; As[f * 4 + 1][r] = x1 + sv.y;
                As[f * 4 + 2][r] = x2 + sv.z; As[f * 4 + 3][r] = x3 + sv.w;
            }
        }
        {   // B stage: 32 k x 256 cols (float weights)
            const int cq = tid & 63, krb = tid >> 6;
            #pragma unroll
            for (int p = 0; p < 8; p++) {
                const int kr = krb + p * 4;
                const float4 wv = *(const float4*)(W + (size_t)(k0 + kr) * 256 + cq * 4);
                *(float4*)&Bs[kr][cq * 4] = wv;
            }
        }
        __syncthreads();
        #pragma unroll
        for (int kk = 0; kk < 32; kk++) {
            const float4 a0 = *(const float4*)&As[kk][tr * 8];
            const float4 a1 = *(const float4*)&As[kk][tr * 8 + 4];
            const float4 b0 = *(const float4*)&Bs[kk][tc * 8];
            const float4 b1 = *(const float4*)&Bs[kk][tc * 8 + 4];
            const float av[8] = {a0.x, a0.y, a0.z, a0.w, a1.x, a1.y, a1.z, a1.w};
            const float bw[8] = {b0.x, b0.y, b0.z, b0.w, b1.x, b1.y, b1.z, b1.w};
            #pragma unroll
            for (int i = 0; i < 8; i++)
                #pragma unroll
                for (int j = 0; j < 8; j++)
                    acc[i][j] = fmaf(av[i], bw[j], acc[i][j]);
        }
        __syncthreads();
    }
    // + bias
    float bb[8], gg[8], be[8];
    #pragma unroll
    for (int j = 0; j < 8; j++) {
        const int c = tc * 8 + j;
        bb[j] = bias[c]; gg[j] = g[c]; be[j] = b[c];
    }
    #pragma unroll
    for (int i = 0; i < 8; i++)
        #pragma unroll
        for (int j = 0; j < 8; j++) acc[i][j] += bb[j];
    // LayerNorm over 256 cols (32 tc-partials per row)
    float* R = &Bs[0][0];   // reuse: R[row*33 + tc], 64*33 floats
    #pragma unroll
    for (int i = 0; i < 8; i++) {
        float s = 0.f;
        #pragma unroll
        for (int j = 0; j < 8; j++) s += acc[i][j];
        R[(tr * 8 + i) * 33 + tc] = s;
    }
    __syncthreads();
    if (tid < 64) {
        float s = 0.f;
        for (int t = 0; t < 32; t++) s += R[tid * 33 + t];
        mu_s[tid] = s * (1.f / 256.f);
    }
    __syncthreads();
    #pragma unroll
    for (int i = 0; i < 8; i++) {
        const float mu = mu_s[tr * 8 + i];
        float s = 0.f;
        #pragma unroll
        for (int j = 0; j < 8; j++) { const float d = acc[i][j] - mu; s += d * d; }
        R[(tr * 8 + i) * 33 + tc] = s;
    }
    __syncthreads();
    if (tid < 64) {
        float s = 0.f;
        for (int t = 0; t < 32; t++) s += R[tid * 33 + t];
        rs_s[tid] = rsqrtf(s * (1.f / 256.f) + EPSV);
    }
    __syncthreads();
    #pragma unroll
    for (int i = 0; i < 8; i++) {
        const int row = brow + tr * 8 + i;
        const float mu = mu_s[tr * 8 + i], rs = rs_s[tr * 8 + i];
        US4 o0, o1;
        o0.x = fb(fmaxf((acc[i][0] - mu) * rs * gg[0] + be[0], 0.f));
        o0.y = fb(fmaxf((acc[i][1] - mu) * rs * gg[1] + be[1], 0.f));
        o0.z = fb(fmaxf((acc[i][2] - mu) * rs * gg[2] + be[2], 0.f));
        o0.w = fb(fmaxf((acc[i][3] - mu) * rs * gg[3] + be[3], 0.f));
        o1.x = fb(fmaxf((acc[i][4] - mu) * rs * gg[4] + be[4], 0.f));
        o1.y = fb(fmaxf((acc[i][5] - mu) * rs * gg[5] + be[5], 0.f));
        o1.z = fb(fmaxf((acc[i][6] - mu) * rs * gg[6] + be[6], 0.f));
        o1.w = fb(fmaxf((acc[i][7] - mu) * rs * gg[7] + be[7], 0.f));
        *(US4*)(OUT + (size_t)row * 256 + tc * 8) = o0;
        *(US4*)(OUT + (size_t)row * 256 + tc * 8 + 4) = o1;
    }
}

// ---------- fuse1: H1 = [vert|X|Y|Z] @ Wf1 + bf1 (bf16 out) + BN1 col stats ----------
// tile 128x128, K=768 (X on the fly, Y, Z)
__global__ __launch_bounds__(256) void k_f1(
    const float2* __restrict__ UW, const float* __restrict__ Wg,
    const float* __restrict__ Bg, const float* __restrict__ Bt,
    const u16* __restrict__ Yb, const u16* __restrict__ Zb,
    const float* __restrict__ W,       // Wf1 + 512 (rows 1..768)
    const float* __restrict__ bias,    // bf1
    const float* __restrict__ vert, const float* __restrict__ w0,  // Wf1 row 0
    u16* __restrict__ H1, float* __restrict__ colsum, float* __restrict__ colsq) {
    __shared__ float As[32][132];
    __shared__ float Bs[32][128];
    __shared__ float sWg[256], sBg[256], sBt[256];
    const int tid = threadIdx.x;
    sWg[tid] = Wg[tid]; sBg[tid] = Bg[tid]; sBt[tid] = Bt[tid];
    __syncthreads();
    const int tr = tid >> 4, tc = tid & 15;
    const int brow = blockIdx.x * 128, bcol = blockIdx.y * 128;
    float acc[8][8] = {};
    for (int k0 = 0; k0 < 768; k0 += 32) {
        {   // A stage
            const int f = tid & 7, r0 = tid >> 3;
            const int kb = (k0 & 255) + f * 4;
            #pragma unroll
            for (int p = 0; p < 4; p++) {
                const int r = r0 + p * 32;
                float x0, x1, x2, x3;
                if (k0 < 256) {
                    const float2 uw = UW[brow + r];
                    x0 = fmaxf(uw.x * sWg[kb + 0] + uw.y * sBg[kb + 0] + sBt[kb + 0], 0.f);
                    x1 = fmaxf(uw.x * sWg[kb + 1] + uw.y * sBg[kb + 1] + sBt[kb + 1], 0.f);
                    x2 = fmaxf(uw.x * sWg[kb + 2] + uw.y * sBg[kb + 2] + sBt[kb + 2], 0.f);
                    x3 = fmaxf(uw.x * sWg[kb + 3] + uw.y * sBg[kb + 3] + sBt[kb + 3], 0.f);
                } else {
                    const u16* Ab = (k0 < 512) ? Yb : Zb;
                    const US4 ua = *(const US4*)(Ab + (size_t)(brow + r) * 256 + kb);
                    x0 = bf(ua.x); x1 = bf(ua.y); x2 = bf(ua.z); x3 = bf(ua.w);
                }
                As[f * 4 + 0][r] = x0; As[f * 4 + 1][r] = x1;
                As[f * 4 + 2][r] = x2; As[f * 4 + 3][r] = x3;
            }
        }
        {   // B stage: W rows k0..k0+31, 128 cols
            const int cq = tid & 31, krb = tid >> 5;
            #pragma unroll
            for (int p = 0; p < 4; p++) {
                const int kr = krb + p * 8;
                const float4 wv = *(const float4*)(W + (size_t)(k0 + kr) * 512 + bcol + cq * 4);
                *(float4*)&Bs[kr][cq * 4] = wv;
            }
        }
        __syncthreads();
        #pragma unroll
        for (int kk = 0; kk < 32; kk++) {
            const float4 a0 = *(const float4*)&As[kk][tr * 8];
            const float4 a1 = *(const float4*)&As[kk][tr * 8 + 4];
            const float4 b0 = *(const float4*)&Bs[kk][tc * 8];
            const float4 b1 = *(const float4*)&Bs[kk][tc * 8 + 4];
            const float av[8] = {a0.x, a0.y, a0.z, a0.w, a1.x, a1.y, a1.z, a1.w};
            const float bw[8] = {b0.x, b0.y, b0.z, b0.w, b1.x, b1.y, b1.z, b1.w};
            #pragma unroll
            for (int i = 0; i < 8; i++)
                #pragma unroll
                for (int j = 0; j < 8; j++)
                    acc[i][j] = fmaf(av[i], bw[j], acc[i][j]);
        }
        __syncthreads();
    }
    // epilogue: v = acc + bf1 + vert*w0 ; store bf16 ; column stats
    float bb[8], w0v[8], vs[8];
    #pragma unroll
    for (int j = 0; j < 8; j++) {
        const int c = bcol + tc * 8 + j;
        bb[j] = bias[c]; w0v[j] = w0[c];
    }
    #pragma unroll
    for (int i = 0; i < 8; i++) vs[i] = vert[brow + tr * 8 + i];
    float2* R2 = (float2*)&As[0][0];   // R2[col*16 + tr]
    float csum[8], csq[8];
    #pragma unroll
    for (int j = 0; j < 8; j++) { csum[j] = 0.f; csq[j] = 0.f; }
    #pragma unroll
    for (int i = 0; i < 8; i++) {
        const int row = brow + tr * 8 + i;
        US4 o0, o1;
        float v[8];
        #pragma unroll
        for (int j = 0; j < 8; j++) {
            v[j] = acc[i][j] + bb[j] + vs[i] * w0v[j];
            csum[j] += v[j]; csq[j] += v[j] * v[j];
        }
        o0.x = fb(v[0]); o0.y = fb(v[1]); o0.z = fb(v[2]); o0.w = fb(v[3]);
        o1.x = fb(v[4]); o1.y = fb(v[5]); o1.z = fb(v[6]); o1.w = fb(v[7]);
        *(US4*)(H1 + (size_t)row * 512 + bcol + tc * 8) = o0;
        *(US4*)(H1 + (size_t)row * 512 + bcol + tc * 8 + 4) = o1;
    }
    #pragma unroll
    for (int j = 0; j < 8; j++) R2[(tc * 8 + j) * 16 + tr] = make_float2(csum[j], csq[j]);
    __syncthreads();
    if (tid < 128) {
        float s = 0.f, q = 0.f;
        for (int t = 0; t < 16; t++) { const float2 p = R2[tid * 16 + t]; s += p.x; q += p.y; }
        atomicAdd(&colsum[bcol + tid], s);
        atomicAdd(&colsq[bcol + tid], q);
    }
}

// ---------- finalize BN: SC[c] = {rs*g, beta - mu*rs*g} ----------
template<int C>
__global__ void k_bnfin(const float* __restrict__ colsum, const float* __restrict__ colsq,
                        const float* __restrict__ g, const float* __restrict__ b,
                        float2* __restrict__ SC) {
    const int c = threadIdx.x;
    const float mu = colsum[c] * (1.f / (float)NN);
    const float var = colsq[c] * (1.f / (float)NN) - mu * mu;
    const float rs = rsqrtf(fmaxf(var, 0.f) + EPSV);
    const float sc = rs * g[c];
    SC[c] = make_float2(sc, b[c] - mu * sc);
}

// ---------- fuse2: h2 = relu(BN1(H1)) @ Wf2 + bf2 (bf16 out) + BN2 col stats ----------
__global__ __launch_bounds__(256) void k_f2(
    const u16* __restrict__ H1, const float2* __restrict__ SC1,
    const float* __restrict__ W,       // Wf2 [512,256]
    const float* __restrict__ bias,    // bf2
    u16* __restrict__ h2, float* __restrict__ colsum, float* __restrict__ colsq) {
    __shared__ float As[32][132];
    __shared__ float Bs[32][128];
    __shared__ float2 sSC[512];
    const int tid = threadIdx.x;
    sSC[tid] = SC1[tid]; sSC[tid + 256] = SC1[tid + 256];
    __syncthreads();
    const int tr = tid >> 4, tc = tid & 15;
    const int brow = blockIdx.x * 128, bcol = blockIdx.y * 128;
    float acc[8][8] = {};
    for (int k0 = 0; k0 < 512; k0 += 32) {
        {   // A stage: relu(BN1) applied on load
            const int f = tid & 7, r0 = tid >> 3;
            const int kb = k0 + f * 4;
            const float2 s0 = sSC[kb + 0], s1 = sSC[kb + 1], s2 = sSC[kb + 2], s3 = sSC[kb + 3];
            #pragma unroll
            for (int p = 0; p < 4; p++) {
                const int r = r0 + p * 32;
                const US4 ua = *(const US4*)(H1 + (size_t)(brow + r) * 512 + kb);
                As[f * 4 + 0][r] = fmaxf(bf(ua.x) * s0.x + s0.y, 0.f);
                As[f * 4 + 1][r] = fmaxf(bf(ua.y) * s1.x + s1.y, 0.f);
                As[f * 4 + 2][r] = fmaxf(bf(ua.z) * s2.x + s2.y, 0.f);
                As[f * 4 + 3][r] = fmaxf(bf(ua.w) * s3.x + s3.y, 0.f);
            }
        }
        {   // B stage
            const int cq = tid & 31, krb = tid >> 5;
            #pragma unroll
            for (int p = 0; p < 4; p++) {
                const int kr = krb + p * 8;
                const float4 wv = *(const float4*)(W + (size_t)(k0 + kr) * 256 + bcol + cq * 4);
                *(float4*)&Bs[kr][cq * 4] = wv;
            }
        }
        __syncthreads();
        #pragma unroll
        for (int kk = 0; kk < 32; kk++) {
            const float4 a0 = *(const float4*)&As[kk][tr * 8];
            const float4 a1 = *(const float4*)&As[kk][tr * 8 + 4];
            const float4 b0 = *(const float4*)&Bs[kk][tc * 8];
            const float4 b1 = *(const float4*)&Bs[kk][tc * 8 + 4];
            const float av[8] = {a0.x, a0.y, a0.z, a0.w, a1.x, a1.y, a1.z, a1.w};
            const float bw[8] = {b0.x, b0.y, b0.z, b0.w, b1.x, b1.y, b1.z, b1.w};
            #pragma unroll
            for (int i = 0; i < 8; i++)
                #pragma unroll
                for (int j = 0; j < 8; j++)
                    acc[i][j] = fmaf(av[i], bw[j], acc[i][j]);
        }
        __syncthreads();
    }
    float bb[8];
    #pragma unroll
    for (int j = 0; j < 8; j++) bb[j] = bias[bcol + tc * 8 + j];
    float2* R2 = (float2*)&As[0][0];
    float csum[8], csq[8];
    #pragma unroll
    for (int j = 0; j < 8; j++) { csum[j] = 0.f; csq[j] = 0.f; }
    #pragma unroll
    for (int i = 0; i < 8; i++) {
        const int row = brow + tr * 8 + i;
        US4 o0, o1;
        float v[8];
        #pragma unroll
        for (int j = 0; j < 8; j++) {
            v[j] = acc[i][j] + bb[j];
            csum[j] += v[j]; csq[j] += v[j] * v[j];
        }
        o0.x = fb(v[0]); o0.y = fb(v[1]); o0.z = fb(v[2]); o0.w = fb(v[3]);
        o1.x = fb(v[4]); o1.y = fb(v[5]); o1.z = fb(v[6]); o1.w = fb(v[7]);
        *(US4*)(h2 + (size_t)row * 256 + bcol + tc * 8) = o0;
        *(US4*)(h2 + (size_t)row * 256 + bcol + tc * 8 + 4) = o1;
    }
    #pragma unroll
    for (int j = 0; j < 8; j++) R2[(tc * 8 + j) * 16 + tr] = make_float2(csum[j], csq[j]);
    __syncthreads();
    if (tid < 128) {
        float s = 0.f, q = 0.f;
        for (int t = 0; t < 16; t++) { const float2 p = R2[tid * 16 + t]; s += p.x; q += p.y; }
        atomicAdd(&colsum[bcol + tid], s);
        atomicAdd(&colsq[bcol + tid], q);
    }
}

// ---------- heads: apply BN2+relu on load, dot with Wa / Wv ----------
__global__ void k_head(const u16* __restrict__ h2, const float2* __restrict__ SC2,
                       const float* __restrict__ Wa, const float* __restrict__ ba,
                       const float* __restrict__ Wv, const float* __restrict__ bv,
                       float* __restrict__ abuf, float* __restrict__ vbuf) {
    const int node = blockIdx.x * 4 + (threadIdx.x >> 6);
    const int lane = threadIdx.x & 63;
    const US4 u = *(const US4*)(h2 + (size_t)node * 256 + lane * 4);
    const float4 wa = *(const float4*)(Wa + lane * 4);
    const float4 wv = *(const float4*)(Wv + lane * 4);
    const float2 s0 = SC2[lane * 4 + 0], s1 = SC2[lane * 4 + 1];
    const float2 s2 = SC2[lane * 4 + 2], s3 = SC2[lane * 4 + 3];
    const float h0 = fmaxf(bf(u.x) * s0.x + s0.y, 0.f);
    const float h1 = fmaxf(bf(u.y) * s1.x + s1.y, 0.f);
    const float h2v = fmaxf(bf(u.z) * s2.x + s2.y, 0.f);
    const float h3 = fmaxf(bf(u.w) * s3.x + s3.y, 0.f);
    float da = h0 * wa.x + h1 * wa.y + h2v * wa.z + h3 * wa.w;
    float dv = h0 * wv.x + h1 * wv.y + h2v * wv.z + h3 * wv.w;
    for (int o = 32; o > 0; o >>= 1) {
        da += __shfl_down(da, o);
        dv += __shfl_down(dv, o);
    }
    if (lane == 0) {
        abuf[node] = da + ba[0];
        vbuf[node] = dv + bv[0];
    }
}

// ---------- logsumexp over all N logits ----------
__global__ void k_lse(const float* __restrict__ a, float* __restrict__ lseb) {
    __shared__ float red[1024];
    const int t = threadIdx.x;
    float m = -3.4e38f;
    for (int i = t; i < NN; i += 1024) m = fmaxf(m, a[i]);
    red[t] = m; __syncthreads();
    for (int o = 512; o > 0; o >>= 1) { if (t < o) red[t] = fmaxf(red[t], red[t + o]); __syncthreads(); }
    const float mx = red[0];
    __syncthreads();
    float s = 0.f;
    for (int i = t; i < NN; i += 1024) s += expf(a[i] - mx);
    red[t] = s; __syncthreads();
    for (int o = 512; o > 0; o >>= 1) { if (t < o) red[t] += red[t + o]; __syncthreads(); }
    if (t == 0) lseb[0] = mx + logf(red[0]);
}

// ---------- act output + graph segment sums ----------
__global__ void k_finish(const float* __restrict__ abuf, const float* __restrict__ vbuf,
                         const int* __restrict__ batch, const float* __restrict__ lseb,
                         float* __restrict__ out_act, float* __restrict__ gsum,
                         float* __restrict__ gcnt) {
    const int i = blockIdx.x * 256 + threadIdx.x;
    out_act[i] = abuf[i] - lseb[0];
    atomicAdd(&gsum[batch[i]], vbuf[i]);
    atomicAdd(&gcnt[batch[i]], 1.f);
}

__global__ void k_val(const float* __restrict__ gsum, const float* __restrict__ gcnt,
                      float* __restrict__ out_val) {
    const int g = blockIdx.x * 256 + threadIdx.x;
    out_val[g] = tanhf(gsum[g] / fmaxf(gcnt[g], 1.f));
}

extern "C" void kernel_launch(void* const* d_in, const int* in_sizes, int n_in,
                              void* d_out, int out_size, void* d_ws, size_t ws_size,
                              hipStream_t stream) {
    const float* vert = (const float*)d_in[0];
    const int* ei   = (const int*)d_in[1];
    const int* batch= (const int*)d_in[2];
    const float* W1  = (const float*)d_in[3];
    const float* b1  = (const float*)d_in[4];
    const float* W2  = (const float*)d_in[5];
    const float* b2  = (const float*)d_in[6];
    const float* W3  = (const float*)d_in[7];
    const float* b3  = (const float*)d_in[8];
    const float* lng = (const float*)d_in[9];
    const float* lnb = (const float*)d_in[10];
    const float* Wf1 = (const float*)d_in[11];
    const float* bf1 = (const float*)d_in[12];
    const float* Wf2 = (const float*)d_in[13];
    const float* bf2 = (const float*)d_in[14];
    const float* bn1g= (const float*)d_in[15];
    const float* bn1b= (const float*)d_in[16];
    const float* bn2g= (const float*)d_in[17];
    const float* bn2b= (const float*)d_in[18];
    const float* Wa  = (const float*)d_in[19];
    const float* ba  = (const float*)d_in[20];
    const float* Wv  = (const float*)d_in[21];
    const float* bv  = (const float*)d_in[22];

    // ---- workspace layout (~238 MB) ----
    // [0, N*1024)          : S (fp32 N*256)  -- later aliased by H1 (bf16 N*512)
    // [N*1024, N*1536)     : Yb (bf16 N*256) -- later aliased by h2 (bf16 N*256)
    // [N*1536, N*2048)     : Zb (bf16 N*256)
    // [N*2048, ...)        : small tail
    const size_t NHB = (size_t)NN * 1024;
    float* S  = (float*)d_ws;
    u16*   H1 = (u16*)d_ws;
    u16*   Yb = (u16*)((char*)d_ws + NHB);
    u16*   Zb = Yb + (size_t)NN * 256;
    u16*   h2 = Yb;
    float* tail = (float*)((char*)d_ws + 2 * NHB);
    float* agg0   = tail;                 // NN
    float2* UW    = (float2*)(agg0 + NN); // NN float2
    float* abuf   = agg0 + 3 * (size_t)NN;
    float* vbuf   = abuf + NN;
    float* Wg     = vbuf + NN;            // 256
    float* Bg     = Wg + 256;
    float* Bt     = Bg + 256;
    float* stat   = Bt + 256;             // 4
    float* colsum = stat + 4;             // 512
    float* colsq  = colsum + 512;         // 512
    float2* SC1   = (float2*)(colsq + 512);   // 512 float2
    float2* SC2   = SC1 + 512;                // 256 float2
    float* gsum   = (float*)(SC2 + 256);  // 512
    float* gcnt   = gsum + 512;           // 512
    float* lseb   = gcnt + 512;           // 1

    float* out = (float*)d_out;

    // ---- layer 1 (closed-form X) ----
    hipMemsetAsync(agg0, 0, (size_t)NN * 4, stream);
    k_edge_s0<<<NE / 256, 256, 0, stream>>>(ei, vert, agg0);
    k_prep<<<1, 256, 0, stream>>>(W1, b1, lng, lnb, Wg, Bg, Bt, stat);
    k_uw<<<NN / 256, 256, 0, stream>>>(vert, agg0, stat, UW);

    // ---- layer 2 ----
    hipMemsetAsync(S, 0, NHB, stream);
    k_aggX<<<2048, 256, 0, stream>>>(ei, UW, Wg, Bg, Bt, S);
    k_gemm_ln<0><<<NN / 64, 256, 0, stream>>>(UW, Wg, Bg, Bt, nullptr, S, W2, b2,
                                              lng, lnb, Yb);

    // ---- layer 3 ----
    hipMemsetAsync(S, 0, NHB, stream);
    k_aggY<<<NE / 4, 256, 0, stream>>>(ei, Yb, S);
    k_gemm_ln<1><<<NN / 64, 256, 0, stream>>>(nullptr, nullptr, nullptr, nullptr, Yb, S,
                                              W3, b3, lng, lnb, Zb);

    // ---- fuse1 (writes H1 over dead S) + BN1 ----
    hipMemsetAsync(colsum, 0, 1024 * 4, stream);
    k_f1<<<dim3(NN / 128, 4), 256, 0, stream>>>(UW, Wg, Bg, Bt, Yb, Zb, Wf1 + 512, bf1,
                                                vert, Wf1, H1, colsum, colsq);
    k_bnfin<512><<<1, 512, 0, stream>>>(colsum, colsq, bn1g, bn1b, SC1);

    // ---- fuse2 (writes h2 over dead Yb) + BN2 ----
    hipMemsetAsync(colsum, 0, 1024 * 4, stream);
    k_f2<<<dim3(NN / 128, 2), 256, 0, stream>>>(H1, SC1, Wf2, bf2, h2, colsum, colsq);
    k_bnfin<256><<<1, 256, 0, stream>>>(colsum, colsq, bn2g, bn2b, SC2);

    // ---- heads ----
    k_head<<<NN / 4, 256, 0, stream>>>(h2, SC2, Wa, ba, Wv, bv, abuf, vbuf);
    k_lse<<<1, 1024, 0, stream>>>(abuf, lseb);
    hipMemsetAsync(gsum, 0, 1024 * 4, stream);
    k_finish<<<NN / 256, 256, 0, stream>>>(abuf, vbuf, batch, lseb, out, gsum, gcnt);
    k_val<<<NG / 256, 256, 0, stream>>>(gsum, gcnt, out + NN);
}

// Round 5
// 2424.794 us; speedup vs baseline: 3.5313x; 3.5313x over previous
//
#include <hip/hip_runtime.h>
#include <hip/hip_bf16.h>

#define NN 115200      // nodes
#define NE 921600      // edges
#define NG 512         // graphs
#define EPSV 1e-5f

typedef unsigned short u16;
struct __align__(8) US4 { u16 x, y, z, w; };

static __device__ __forceinline__ float bf(u16 u) {
    return __uint_as_float(((unsigned)u) << 16);
}
static __device__ __forceinline__ u16 fb(float f) {
    unsigned u = __float_as_uint(f);
    return (u16)((u + 0x7FFFu + ((u >> 16) & 1u)) >> 16);   // RNE
}

// ================= CSR build (dst-sorted) =================
__global__ void k_hist(const int* __restrict__ ei, int* __restrict__ cnt) {
    const int e = blockIdx.x * 256 + threadIdx.x;
    atomicAdd(&cnt[ei[NE + e]], 1);
}

// block-level Hillis-Steele scan; rowptr[i] = exclusive-within-block, psum[b] = block total
__global__ void k_scan1(const int* __restrict__ cnt, int* __restrict__ rowptr,
                        int* __restrict__ psum) {
    __shared__ int sh[256];
    const int t = threadIdx.x, i = blockIdx.x * 256 + t;
    const int v = cnt[i];
    sh[t] = v; __syncthreads();
    for (int o = 1; o < 256; o <<= 1) {
        const int tv = (t >= o) ? sh[t - o] : 0;
        __syncthreads();
        sh[t] += tv;
        __syncthreads();
    }
    rowptr[i] = sh[t] - v;
    if (t == 255) psum[blockIdx.x] = sh[255];
}

__global__ void k_scan2(const int* __restrict__ psum, int* __restrict__ poff) {
    __shared__ int sh[512];
    const int t = threadIdx.x;
    const int v = (t < 450) ? psum[t] : 0;
    sh[t] = v; __syncthreads();
    for (int o = 1; o < 512; o <<= 1) {
        const int tv = (t >= o) ? sh[t - o] : 0;
        __syncthreads();
        sh[t] += tv;
        __syncthreads();
    }
    if (t < 450) poff[t] = sh[t] - v;
}

__global__ void k_scan3(int* __restrict__ rowptr, const int* __restrict__ poff) {
    const int i = blockIdx.x * 256 + threadIdx.x;
    rowptr[i] += poff[blockIdx.x];
    if (i == 0) rowptr[NN] = NE;
}

__global__ void k_fill(const int* __restrict__ ei, const int* __restrict__ rowptr,
                       int* __restrict__ cur, int* __restrict__ col) {
    const int e = blockIdx.x * 256 + threadIdx.x;
    const int d = ei[NE + e];
    const int p = rowptr[d] + atomicAdd(&cur[d], 1);
    col[p] = ei[e];
}

// ---------- W1/b1 closed-form LN stats + per-feature vectors ----------
// X[r,j] = relu(u_r*Wg[j] + w_r*Bg[j] + Bt[j]),  u=s0*rs, w=rs
__global__ void k_prep(const float* __restrict__ W1, const float* __restrict__ b1,
                       const float* __restrict__ lng, const float* __restrict__ lnb,
                       float* __restrict__ Wg, float* __restrict__ Bg,
                       float* __restrict__ Bt, float* __restrict__ stat) {
    const int j = threadIdx.x;
    const float w = W1[j], b = b1[j];
    __shared__ float r1[256], r2[256], r3[256];
    r1[j] = w; r2[j] = b; __syncthreads();
    for (int o = 128; o > 0; o >>= 1) {
        if (j < o) { r1[j] += r1[j + o]; r2[j] += r2[j + o]; }
        __syncthreads();
    }
    const float mW = r1[0] * (1.f / 256.f), mB = r2[0] * (1.f / 256.f);
    __syncthreads();
    const float dw = w - mW, db = b - mB;
    r1[j] = dw * dw; r2[j] = db * db; r3[j] = dw * db; __syncthreads();
    for (int o = 128; o > 0; o >>= 1) {
        if (j < o) { r1[j] += r1[j + o]; r2[j] += r2[j + o]; r3[j] += r3[j + o]; }
        __syncthreads();
    }
    if (j == 0) { stat[0] = r1[0] * (1.f / 256.f); stat[1] = r3[0] * (1.f / 256.f);
                  stat[2] = r2[0] * (1.f / 256.f); }
    const float gj = lng[j];
    Wg[j] = dw * gj; Bg[j] = db * gj; Bt[j] = lnb[j];
}

// ---------- per-node s0 (CSR gather) + u,w scalars ----------
__global__ void k_s0uw(const float* __restrict__ vert, const int* __restrict__ rowptr,
                       const int* __restrict__ col, const float* __restrict__ stat,
                       float2* __restrict__ UW) {
    const int r = blockIdx.x * 256 + threadIdx.x;
    float s0 = vert[r];
    const int b = rowptr[r], e = rowptr[r + 1];
    for (int k = b; k < e; k++) s0 += vert[col[k]];
    const float var = s0 * s0 * stat[0] + 2.f * s0 * stat[1] + stat[2];
    const float rs = rsqrtf(var + EPSV);
    UW[r] = make_float2(s0 * rs, rs);
}

// ---------- layer-2 aggregation (CSR gather, X on the fly) ----------
__global__ void k_aggX_csr(const int* __restrict__ rowptr, const int* __restrict__ col,
                           const float2* __restrict__ UW, const float* __restrict__ Wg,
                           const float* __restrict__ Bg, const float* __restrict__ Bt,
                           float* __restrict__ S) {
    __shared__ float sWg[256], sBg[256], sBt[256];
    const int tid = threadIdx.x;
    sWg[tid] = Wg[tid]; sBg[tid] = Bg[tid]; sBt[tid] = Bt[tid];
    __syncthreads();
    const int d = blockIdx.x * 4 + (tid >> 6);
    const int j = (tid & 63) * 4;
    const float w0 = sWg[j + 0], w1 = sWg[j + 1], w2 = sWg[j + 2], w3 = sWg[j + 3];
    const float g0 = sBg[j + 0], g1 = sBg[j + 1], g2 = sBg[j + 2], g3 = sBg[j + 3];
    const float t0 = sBt[j + 0], t1 = sBt[j + 1], t2 = sBt[j + 2], t3 = sBt[j + 3];
    float a0 = 0.f, a1 = 0.f, a2 = 0.f, a3 = 0.f;
    const int b = rowptr[d], e = rowptr[d + 1];
    for (int k = b; k < e; k++) {
        const float2 uw = UW[col[k]];
        a0 += fmaxf(uw.x * w0 + uw.y * g0 + t0, 0.f);
        a1 += fmaxf(uw.x * w1 + uw.y * g1 + t1, 0.f);
        a2 += fmaxf(uw.x * w2 + uw.y * g2 + t2, 0.f);
        a3 += fmaxf(uw.x * w3 + uw.y * g3 + t3, 0.f);
    }
    *(float4*)(S + (size_t)d * 256 + j) = make_float4(a0, a1, a2, a3);
}

// ---------- layer-3 aggregation (CSR gather of bf16 Y rows) ----------
__global__ void k_aggY_csr(const int* __restrict__ rowptr, const int* __restrict__ col,
                           const u16* __restrict__ Y, float* __restrict__ S) {
    const int tid = threadIdx.x;
    const int d = blockIdx.x * 4 + (tid >> 6);
    const int j = (tid & 63) * 4;
    float a0 = 0.f, a1 = 0.f, a2 = 0.f, a3 = 0.f;
    const int b = rowptr[d], e = rowptr[d + 1];
    for (int k = b; k < e; k++) {
        const US4 u = *(const US4*)(Y + (size_t)col[k] * 256 + j);
        a0 += bf(u.x); a1 += bf(u.y); a2 += bf(u.z); a3 += bf(u.w);
    }
    *(float4*)(S + (size_t)d * 256 + j) = make_float4(a0, a1, a2, a3);
}

// ---------- GIN GEMM with fused LayerNorm+ReLU epilogue ----------
// OUT = relu(LN((A + S) @ W + bias)), A = X_otf (SRC=0) or bf16 Ab (SRC=1)
// tile: 64 rows x 256 cols (full row per block), 256 threads, 8x8 acc
template<int SRC>
__global__ __launch_bounds__(256) void k_gemm_ln(
    const float2* __restrict__ UW, const float* __restrict__ Wg,
    const float* __restrict__ Bg, const float* __restrict__ Bt,
    const u16* __restrict__ Ab, const float* __restrict__ S,
    const float* __restrict__ W, const float* __restrict__ bias,
    const float* __restrict__ g, const float* __restrict__ b,
    u16* __restrict__ OUT) {
    __shared__ float As[32][68];    // [k][row], row-stride 272B
    __shared__ float Bs[32][256];   // [k][col]
    __shared__ float mu_s[64], rs_s[64];
    const int tid = threadIdx.x;
    const int brow = blockIdx.x * 64;
    const int tr = tid >> 5, tc = tid & 31;   // 8 x 32 threads -> rows 8x8, cols 32x8
    float acc[8][8] = {};
    for (int k0 = 0; k0 < 256; k0 += 32) {
        {   // A stage: 64 rows x 32 k
            const int f = tid & 7, r0 = tid >> 3;
            #pragma unroll
            for (int p = 0; p < 2; p++) {
                const int r = r0 + p * 32;
                const float4 sv = *(const float4*)&S[(size_t)(brow + r) * 256 + k0 + f * 4];
                float x0, x1, x2, x3;
                if (SRC == 0) {
                    const float2 uw = UW[brow + r];
                    const int kb = k0 + f * 4;
                    x0 = fmaxf(uw.x * Wg[kb + 0] + uw.y * Bg[kb + 0] + Bt[kb + 0], 0.f);
                    x1 = fmaxf(uw.x * Wg[kb + 1] + uw.y * Bg[kb + 1] + Bt[kb + 1], 0.f);
                    x2 = fmaxf(uw.x * Wg[kb + 2] + uw.y * Bg[kb + 2] + Bt[kb + 2], 0.f);
                    x3 = fmaxf(uw.x * Wg[kb + 3] + uw.y * Bg[kb + 3] + Bt[kb + 3], 0.f);
                } else {
                    const US4 ua = *(const US4*)(Ab + (size_t)(brow + r) * 256 + k0 + f * 4);
                    x0 = bf(ua.x); x1 = bf(ua.y); x2 = bf(ua.z); x3 = bf(ua.w);
                }
                As[f * 4 + 0][r] = x0 + sv.x; As[f * 4 + 1][r] = x1 + sv.y;
                As[f * 4 + 2][r] = x2 + sv.z; As[f * 4 + 3][r] = x3 + sv.w;
            }
        }
        {   // B stage: 32 k x 256 cols (float weights)
            const int cq = tid & 63, krb = tid >> 6;
            #pragma unroll
            for (int p = 0; p < 8; p++) {
                const int kr = krb + p * 4;
                const float4 wv = *(const float4*)(W + (size_t)(k0 + kr) * 256 + cq * 4);
                *(float4*)&Bs[kr][cq * 4] = wv;
            }
        }
        __syncthreads();
        #pragma unroll
        for (int kk = 0; kk < 32; kk++) {
            const float4 a0 = *(const float4*)&As[kk][tr * 8];
            const float4 a1 = *(const float4*)&As[kk][tr * 8 + 4];
            const float4 b0 = *(const float4*)&Bs[kk][tc * 8];
            const float4 b1 = *(const float4*)&Bs[kk][tc * 8 + 4];
            const float av[8] = {a0.x, a0.y, a0.z, a0.w, a1.x, a1.y, a1.z, a1.w};
            const float bw[8] = {b0.x, b0.y, b0.z, b0.w, b1.x, b1.y, b1.z, b1.w};
            #pragma unroll
            for (int i = 0; i < 8; i++)
                #pragma unroll
                for (int j = 0; j < 8; j++)
                    acc[i][j] = fmaf(av[i], bw[j], acc[i][j]);
        }
        __syncthreads();
    }
    // + bias
    float bb[8], gg[8], be[8];
    #pragma unroll
    for (int j = 0; j < 8; j++) {
        const int c = tc * 8 + j;
        bb[j] = bias[c]; gg[j] = g[c]; be[j] = b[c];
    }
    #pragma unroll
    for (int i = 0; i < 8; i++)
        #pragma unroll
        for (int j = 0; j < 8; j++) acc[i][j] += bb[j];
    // LayerNorm over 256 cols (32 tc-partials per row)
    float* R = &Bs[0][0];   // reuse: R[row*33 + tc], 64*33 floats
    #pragma unroll
    for (int i = 0; i < 8; i++) {
        float s = 0.f;
        #pragma unroll
        for (int j = 0; j < 8; j++) s += acc[i][j];
        R[(tr * 8 + i) * 33 + tc] = s;
    }
    __syncthreads();
    if (tid < 64) {
        float s = 0.f;
        for (int t = 0; t < 32; t++) s += R[tid * 33 + t];
        mu_s[tid] = s * (1.f / 256.f);
    }
    __syncthreads();
    #pragma unroll
    for (int i = 0; i < 8; i++) {
        const float mu = mu_s[tr * 8 + i];
        float s = 0.f;
        #pragma unroll
        for (int j = 0; j < 8; j++) { const float d = acc[i][j] - mu; s += d * d; }
        R[(tr * 8 + i) * 33 + tc] = s;
    }
    __syncthreads();
    if (tid < 64) {
        float s = 0.f;
        for (int t = 0; t < 32; t++) s += R[tid * 33 + t];
        rs_s[tid] = rsqrtf(s * (1.f / 256.f) + EPSV);
    }
    __syncthreads();
    #pragma unroll
    for (int i = 0; i < 8; i++) {
        const int row = brow + tr * 8 + i;
        const float mu = mu_s[tr * 8 + i], rs = rs_s[tr * 8 + i];
        US4 o0, o1;
        o0.x = fb(fmaxf((acc[i][0] - mu) * rs * gg[0] + be[0], 0.f));
        o0.y = fb(fmaxf((acc[i][1] - mu) * rs * gg[1] + be[1], 0.f));
        o0.z = fb(fmaxf((acc[i][2] - mu) * rs * gg[2] + be[2], 0.f));
        o0.w = fb(fmaxf((acc[i][3] - mu) * rs * gg[3] + be[3], 0.f));
        o1.x = fb(fmaxf((acc[i][4] - mu) * rs * gg[4] + be[4], 0.f));
        o1.y = fb(fmaxf((acc[i][5] - mu) * rs * gg[5] + be[5], 0.f));
        o1.z = fb(fmaxf((acc[i][6] - mu) * rs * gg[6] + be[6], 0.f));
        o1.w = fb(fmaxf((acc[i][7] - mu) * rs * gg[7] + be[7], 0.f));
        *(US4*)(OUT + (size_t)row * 256 + tc * 8) = o0;
        *(US4*)(OUT + (size_t)row * 256 + tc * 8 + 4) = o1;
    }
}

// ---------- fuse1: H1 = [vert|X|Y|Z] @ Wf1 + bf1 (bf16 out) + BN1 col stats ----------
// tile 128x128, K=768 (X on the fly, Y, Z)
__global__ __launch_bounds__(256) void k_f1(
    const float2* __restrict__ UW, const float* __restrict__ Wg,
    const float* __restrict__ Bg, const float* __restrict__ Bt,
    const u16* __restrict__ Yb, const u16* __restrict__ Zb,
    const float* __restrict__ W,       // Wf1 + 512 (rows 1..768)
    const float* __restrict__ bias,    // bf1
    const float* __restrict__ vert, const float* __restrict__ w0,  // Wf1 row 0
    u16* __restrict__ H1, float* __restrict__ colsum, float* __restrict__ colsq) {
    __shared__ float As[32][132];
    __shared__ float Bs[32][128];
    __shared__ float sWg[256], sBg[256], sBt[256];
    const int tid = threadIdx.x;
    sWg[tid] = Wg[tid]; sBg[tid] = Bg[tid]; sBt[tid] = Bt[tid];
    __syncthreads();
    const int tr = tid >> 4, tc = tid & 15;
    const int brow = blockIdx.x * 128, bcol = blockIdx.y * 128;
    float acc[8][8] = {};
    for (int k0 = 0; k0 < 768; k0 += 32) {
        {   // A stage
            const int f = tid & 7, r0 = tid >> 3;
            const int kb = (k0 & 255) + f * 4;
            #pragma unroll
            for (int p = 0; p < 4; p++) {
                const int r = r0 + p * 32;
                float x0, x1, x2, x3;
                if (k0 < 256) {
                    const float2 uw = UW[brow + r];
                    x0 = fmaxf(uw.x * sWg[kb + 0] + uw.y * sBg[kb + 0] + sBt[kb + 0], 0.f);
                    x1 = fmaxf(uw.x * sWg[kb + 1] + uw.y * sBg[kb + 1] + sBt[kb + 1], 0.f);
                    x2 = fmaxf(uw.x * sWg[kb + 2] + uw.y * sBg[kb + 2] + sBt[kb + 2], 0.f);
                    x3 = fmaxf(uw.x * sWg[kb + 3] + uw.y * sBg[kb + 3] + sBt[kb + 3], 0.f);
                } else {
                    const u16* Ab = (k0 < 512) ? Yb : Zb;
                    const US4 ua = *(const US4*)(Ab + (size_t)(brow + r) * 256 + kb);
                    x0 = bf(ua.x); x1 = bf(ua.y); x2 = bf(ua.z); x3 = bf(ua.w);
                }
                As[f * 4 + 0][r] = x0; As[f * 4 + 1][r] = x1;
                As[f * 4 + 2][r] = x2; As[f * 4 + 3][r] = x3;
            }
        }
        {   // B stage: W rows k0..k0+31, 128 cols
            const int cq = tid & 31, krb = tid >> 5;
            #pragma unroll
            for (int p = 0; p < 4; p++) {
                const int kr = krb + p * 8;
                const float4 wv = *(const float4*)(W + (size_t)(k0 + kr) * 512 + bcol + cq * 4);
                *(float4*)&Bs[kr][cq * 4] = wv;
            }
        }
        __syncthreads();
        #pragma unroll
        for (int kk = 0; kk < 32; kk++) {
            const float4 a0 = *(const float4*)&As[kk][tr * 8];
            const float4 a1 = *(const float4*)&As[kk][tr * 8 + 4];
            const float4 b0 = *(const float4*)&Bs[kk][tc * 8];
            const float4 b1 = *(const float4*)&Bs[kk][tc * 8 + 4];
            const float av[8] = {a0.x, a0.y, a0.z, a0.w, a1.x, a1.y, a1.z, a1.w};
            const float bw[8] = {b0.x, b0.y, b0.z, b0.w, b1.x, b1.y, b1.z, b1.w};
            #pragma unroll
            for (int i = 0; i < 8; i++)
                #pragma unroll
                for (int j = 0; j < 8; j++)
                    acc[i][j] = fmaf(av[i], bw[j], acc[i][j]);
        }
        __syncthreads();
    }
    // epilogue: v = acc + bf1 + vert*w0 ; store bf16 ; column stats
    float bb[8], w0v[8], vs[8];
    #pragma unroll
    for (int j = 0; j < 8; j++) {
        const int c = bcol + tc * 8 + j;
        bb[j] = bias[c]; w0v[j] = w0[c];
    }
    #pragma unroll
    for (int i = 0; i < 8; i++) vs[i] = vert[brow + tr * 8 + i];
    float2* R2 = (float2*)&As[0][0];   // R2[col*16 + tr]
    float csum[8], csq[8];
    #pragma unroll
    for (int j = 0; j < 8; j++) { csum[j] = 0.f; csq[j] = 0.f; }
    #pragma unroll
    for (int i = 0; i < 8; i++) {
        const int row = brow + tr * 8 + i;
        US4 o0, o1;
        float v[8];
        #pragma unroll
        for (int j = 0; j < 8; j++) {
            v[j] = acc[i][j] + bb[j] + vs[i] * w0v[j];
            csum[j] += v[j]; csq[j] += v[j] * v[j];
        }
        o0.x = fb(v[0]); o0.y = fb(v[1]); o0.z = fb(v[2]); o0.w = fb(v[3]);
        o1.x = fb(v[4]); o1.y = fb(v[5]); o1.z = fb(v[6]); o1.w = fb(v[7]);
        *(US4*)(H1 + (size_t)row * 512 + bcol + tc * 8) = o0;
        *(US4*)(H1 + (size_t)row * 512 + bcol + tc * 8 + 4) = o1;
    }
    #pragma unroll
    for (int j = 0; j < 8; j++) R2[(tc * 8 + j) * 16 + tr] = make_float2(csum[j], csq[j]);
    __syncthreads();
    if (tid < 128) {
        float s = 0.f, q = 0.f;
        for (int t = 0; t < 16; t++) { const float2 p = R2[tid * 16 + t]; s += p.x; q += p.y; }
        atomicAdd(&colsum[bcol + tid], s);
        atomicAdd(&colsq[bcol + tid], q);
    }
}

// ---------- finalize BN: SC[c] = {rs*g, beta - mu*rs*g} ----------
template<int C>
__global__ void k_bnfin(const float* __restrict__ colsum, const float* __restrict__ colsq,
                        const float* __restrict__ g, const float* __restrict__ b,
                        float2* __restrict__ SC) {
    const int c = threadIdx.x;
    const float mu = colsum[c] * (1.f / (float)NN);
    const float var = colsq[c] * (1.f / (float)NN) - mu * mu;
    const float rs = rsqrtf(fmaxf(var, 0.f) + EPSV);
    const float sc = rs * g[c];
    SC[c] = make_float2(sc, b[c] - mu * sc);
}

// ---------- fuse2: h2 = relu(BN1(H1)) @ Wf2 + bf2 (bf16 out) + BN2 col stats ----------
__global__ __launch_bounds__(256) void k_f2(
    const u16* __restrict__ H1, const float2* __restrict__ SC1,
    const float* __restrict__ W,       // Wf2 [512,256]
    const float* __restrict__ bias,    // bf2
    u16* __restrict__ h2, float* __restrict__ colsum, float* __restrict__ colsq) {
    __shared__ float As[32][132];
    __shared__ float Bs[32][128];
    __shared__ float2 sSC[512];
    const int tid = threadIdx.x;
    sSC[tid] = SC1[tid]; sSC[tid + 256] = SC1[tid + 256];
    __syncthreads();
    const int tr = tid >> 4, tc = tid & 15;
    const int brow = blockIdx.x * 128, bcol = blockIdx.y * 128;
    float acc[8][8] = {};
    for (int k0 = 0; k0 < 512; k0 += 32) {
        {   // A stage: relu(BN1) applied on load
            const int f = tid & 7, r0 = tid >> 3;
            const int kb = k0 + f * 4;
            const float2 s0 = sSC[kb + 0], s1 = sSC[kb + 1], s2 = sSC[kb + 2], s3 = sSC[kb + 3];
            #pragma unroll
            for (int p = 0; p < 4; p++) {
                const int r = r0 + p * 32;
                const US4 ua = *(const US4*)(H1 + (size_t)(brow + r) * 512 + kb);
                As[f * 4 + 0][r] = fmaxf(bf(ua.x) * s0.x + s0.y, 0.f);
                As[f * 4 + 1][r] = fmaxf(bf(ua.y) * s1.x + s1.y, 0.f);
                As[f * 4 + 2][r] = fmaxf(bf(ua.z) * s2.x + s2.y, 0.f);
                As[f * 4 + 3][r] = fmaxf(bf(ua.w) * s3.x + s3.y, 0.f);
            }
        }
        {   // B stage
            const int cq = tid & 31, krb = tid >> 5;
            #pragma unroll
            for (int p = 0; p < 4; p++) {
                const int kr = krb + p * 8;
                const float4 wv = *(const float4*)(W + (size_t)(k0 + kr) * 256 + bcol + cq * 4);
                *(float4*)&Bs[kr][cq * 4] = wv;
            }
        }
        __syncthreads();
        #pragma unroll
        for (int kk = 0; kk < 32; kk++) {
            const float4 a0 = *(const float4*)&As[kk][tr * 8];
            const float4 a1 = *(const float4*)&As[kk][tr * 8 + 4];
            const float4 b0 = *(const float4*)&Bs[kk][tc * 8];
            const float4 b1 = *(const float4*)&Bs[kk][tc * 8 + 4];
            const float av[8] = {a0.x, a0.y, a0.z, a0.w, a1.x, a1.y, a1.z, a1.w};
            const float bw[8] = {b0.x, b0.y, b0.z, b0.w, b1.x, b1.y, b1.z, b1.w};
            #pragma unroll
            for (int i = 0; i < 8; i++)
                #pragma unroll
                for (int j = 0; j < 8; j++)
                    acc[i][j] = fmaf(av[i], bw[j], acc[i][j]);
        }
        __syncthreads();
    }
    float bb[8];
    #pragma unroll
    for (int j = 0; j < 8; j++) bb[j] = bias[bcol + tc * 8 + j];
    float2* R2 = (float2*)&As[0][0];
    float csum[8], csq[8];
    #pragma unroll
    for (int j = 0; j < 8; j++) { csum[j] = 0.f; csq[j] = 0.f; }
    #pragma unroll
    for (int i = 0; i < 8; i++) {
        const int row = brow + tr * 8 + i;
        US4 o0, o1;
        float v[8];
        #pragma unroll
        for (int j = 0; j < 8; j++) {
            v[j] = acc[i][j] + bb[j];
            csum[j] += v[j]; csq[j] += v[j] * v[j];
        }
        o0.x = fb(v[0]); o0.y = fb(v[1]); o0.z = fb(v[2]); o0.w = fb(v[3]);
        o1.x = fb(v[4]); o1.y = fb(v[5]); o1.z = fb(v[6]); o1.w = fb(v[7]);
        *(US4*)(h2 + (size_t)row * 256 + bcol + tc * 8) = o0;
        *(US4*)(h2 + (size_t)row * 256 + bcol + tc * 8 + 4) = o1;
    }
    #pragma unroll
    for (int j = 0; j < 8; j++) R2[(tc * 8 + j) * 16 + tr] = make_float2(csum[j], csq[j]);
    __syncthreads();
    if (tid < 128) {
        float s = 0.f, q = 0.f;
        for (int t = 0; t < 16; t++) { const float2 p = R2[tid * 16 + t]; s += p.x; q += p.y; }
        atomicAdd(&colsum[bcol + tid], s);
        atomicAdd(&colsq[bcol + tid], q);
    }
}

// ---------- heads: apply BN2+relu on load, dot with Wa / Wv ----------
__global__ void k_head(const u16* __restrict__ h2, const float2* __restrict__ SC2,
                       const float* __restrict__ Wa, const float* __restrict__ ba,
                       const float* __restrict__ Wv, const float* __restrict__ bv,
                       float* __restrict__ abuf, float* __restrict__ vbuf) {
    const int node = blockIdx.x * 4 + (threadIdx.x >> 6);
    const int lane = threadIdx.x & 63;
    const US4 u = *(const US4*)(h2 + (size_t)node * 256 + lane * 4);
    const float4 wa = *(const float4*)(Wa + lane * 4);
    const float4 wv = *(const float4*)(Wv + lane * 4);
    const float2 s0 = SC2[lane * 4 + 0], s1 = SC2[lane * 4 + 1];
    const float2 s2 = SC2[lane * 4 + 2], s3 = SC2[lane * 4 + 3];
    const float h0 = fmaxf(bf(u.x) * s0.x + s0.y, 0.f);
    const float h1 = fmaxf(bf(u.y) * s1.x + s1.y, 0.f);
    const float h2v = fmaxf(bf(u.z) * s2.x + s2.y, 0.f);
    const float h3 = fmaxf(bf(u.w) * s3.x + s3.y, 0.f);
    float da = h0 * wa.x + h1 * wa.y + h2v * wa.z + h3 * wa.w;
    float dv = h0 * wv.x + h1 * wv.y + h2v * wv.z + h3 * wv.w;
    for (int o = 32; o > 0; o >>= 1) {
        da += __shfl_down(da, o);
        dv += __shfl_down(dv, o);
    }
    if (lane == 0) {
        abuf[node] = da + ba[0];
        vbuf[node] = dv + bv[0];
    }
}

// ---------- logsumexp: parallel partials + combine ----------
__global__ void k_lse_part(const float* __restrict__ a, float2* __restrict__ part) {
    __shared__ float red[512];
    const int t = threadIdx.x;
    const float v = a[blockIdx.x * 512 + t];
    red[t] = v; __syncthreads();
    for (int o = 256; o > 0; o >>= 1) { if (t < o) red[t] = fmaxf(red[t], red[t + o]); __syncthreads(); }
    const float m = red[0];
    __syncthreads();
    red[t] = expf(v - m); __syncthreads();
    for (int o = 256; o > 0; o >>= 1) { if (t < o) red[t] += red[t + o]; __syncthreads(); }
    if (t == 0) part[blockIdx.x] = make_float2(m, red[0]);
}

__global__ void k_lse_comb(const float2* __restrict__ part, float* __restrict__ lseb) {
    __shared__ float rm[256], rsum[256];
    const int t = threadIdx.x;
    const float2 p = (t < 225) ? part[t] : make_float2(-3.4e38f, 0.f);
    rm[t] = p.x; __syncthreads();
    for (int o = 128; o > 0; o >>= 1) { if (t < o) rm[t] = fmaxf(rm[t], rm[t + o]); __syncthreads(); }
    const float M = rm[0];
    __syncthreads();
    rsum[t] = p.y * expf(p.x - M); __syncthreads();
    for (int o = 128; o > 0; o >>= 1) { if (t < o) rsum[t] += rsum[t + o]; __syncthreads(); }
    if (t == 0) lseb[0] = M + logf(rsum[0]);
}

// ---------- act output + graph segment sums ----------
__global__ void k_finish(const float* __restrict__ abuf, const float* __restrict__ vbuf,
                         const int* __restrict__ batch, const float* __restrict__ lseb,
                         float* __restrict__ out_act, float* __restrict__ gsum,
                         float* __restrict__ gcnt) {
    const int i = blockIdx.x * 256 + threadIdx.x;
    out_act[i] = abuf[i] - lseb[0];
    atomicAdd(&gsum[batch[i]], vbuf[i]);
    atomicAdd(&gcnt[batch[i]], 1.f);
}

__global__ void k_val(const float* __restrict__ gsum, const float* __restrict__ gcnt,
                      float* __restrict__ out_val) {
    const int g = blockIdx.x * 256 + threadIdx.x;
    out_val[g] = tanhf(gsum[g] / fmaxf(gcnt[g], 1.f));
}

extern "C" void kernel_launch(void* const* d_in, const int* in_sizes, int n_in,
                              void* d_out, int out_size, void* d_ws, size_t ws_size,
                              hipStream_t stream) {
    const float* vert = (const float*)d_in[0];
    const int* ei   = (const int*)d_in[1];
    const int* batch= (const int*)d_in[2];
    const float* W1  = (const float*)d_in[3];
    const float* b1  = (const float*)d_in[4];
    const float* W2  = (const float*)d_in[5];
    const float* b2  = (const float*)d_in[6];
    const float* W3  = (const float*)d_in[7];
    const float* b3  = (const float*)d_in[8];
    const float* lng = (const float*)d_in[9];
    const float* lnb = (const float*)d_in[10];
    const float* Wf1 = (const float*)d_in[11];
    const float* bf1 = (const float*)d_in[12];
    const float* Wf2 = (const float*)d_in[13];
    const float* bf2 = (const float*)d_in[14];
    const float* bn1g= (const float*)d_in[15];
    const float* bn1b= (const float*)d_in[16];
    const float* bn2g= (const float*)d_in[17];
    const float* bn2b= (const float*)d_in[18];
    const float* Wa  = (const float*)d_in[19];
    const float* ba  = (const float*)d_in[20];
    const float* Wv  = (const float*)d_in[21];
    const float* bv  = (const float*)d_in[22];

    // ---- workspace layout (~241.5 MB) ----
    // [0, NHB)             : S (fp32 N*256)  -- later aliased by H1 (bf16 N*512)
    // [NHB, NHB+N*512)     : Yb (bf16 N*256) -- later aliased by h2
    // [NHB+N*512, 2*NHB)   : Zb (bf16 N*256)
    // [2*NHB, ...)         : tail (UW, CSR arrays, small stats)
    const size_t NHB = (size_t)NN * 1024;
    float* S  = (float*)d_ws;
    u16*   H1 = (u16*)d_ws;
    u16*   Yb = (u16*)((char*)d_ws + NHB);
    u16*   Zb = Yb + (size_t)NN * 256;
    u16*   h2 = Yb;
    float* tail = (float*)((char*)d_ws + 2 * NHB);
    float2* UW    = (float2*)tail;            // NN float2 (2NN floats)
    float* Wg     = tail + 2 * (size_t)NN;    // 256
    float* Bg     = Wg + 256;
    float* Bt     = Bg + 256;
    float* stat   = Bt + 256;                 // 4
    float* colsum = stat + 4;                 // 512
    float* colsq  = colsum + 512;             // 512
    float2* SC1   = (float2*)(colsq + 512);   // 512 float2
    float2* SC2   = SC1 + 512;                // 256 float2
    float* gsum   = (float*)(SC2 + 256);      // 512
    float* gcnt   = gsum + 512;               // 512
    float* lseb   = gcnt + 512;               // 1 (+pad)
    float2* lsepart = (float2*)(lseb + 4);    // 225 float2 -> 456 floats
    int*   cnt    = (int*)(lseb + 4 + 456);   // NN
    int*   rowptr = cnt + NN;                 // NN+1 (+pad 3)
    int*   psum   = rowptr + NN + 4;          // 512
    int*   poff   = psum + 512;               // 512
    int*   col    = poff + 512;               // NE
    float* abuf   = (float*)col;              // aliases col (dead by k_head time)
    float* vbuf   = abuf + NN;

    float* out = (float*)d_out;

    // ---- CSR build (dst-sorted), reused by all aggregations ----
    hipMemsetAsync(cnt, 0, (size_t)NN * 4, stream);
    k_hist<<<NE / 256, 256, 0, stream>>>(ei, cnt);
    k_scan1<<<NN / 256, 256, 0, stream>>>(cnt, rowptr, psum);
    k_scan2<<<1, 512, 0, stream>>>(psum, poff);
    k_scan3<<<NN / 256, 256, 0, stream>>>(rowptr, poff);
    hipMemsetAsync(cnt, 0, (size_t)NN * 4, stream);
    k_fill<<<NE / 256, 256, 0, stream>>>(ei, rowptr, cnt, col);

    // ---- layer 1 (closed-form X) ----
    k_prep<<<1, 256, 0, stream>>>(W1, b1, lng, lnb, Wg, Bg, Bt, stat);
    k_s0uw<<<NN / 256, 256, 0, stream>>>(vert, rowptr, col, stat, UW);

    // ---- layer 2 ----
    k_aggX_csr<<<NN / 4, 256, 0, stream>>>(rowptr, col, UW, Wg, Bg, Bt, S);
    k_gemm_ln<0><<<NN / 64, 256, 0, stream>>>(UW, Wg, Bg, Bt, nullptr, S, W2, b2,
                                              lng, lnb, Yb);

    // ---- layer 3 ----
    k_aggY_csr<<<NN / 4, 256, 0, stream>>>(rowptr, col, Yb, S);
    k_gemm_ln<1><<<NN / 64, 256, 0, stream>>>(nullptr, nullptr, nullptr, nullptr, Yb, S,
                                              W3, b3, lng, lnb, Zb);

    // ---- fuse1 (writes H1 over dead S) + BN1 ----
    hipMemsetAsync(colsum, 0, 1024 * 4, stream);
    k_f1<<<dim3(NN / 128, 4), 256, 0, stream>>>(UW, Wg, Bg, Bt, Yb, Zb, Wf1 + 512, bf1,
                                                vert, Wf1, H1, colsum, colsq);
    k_bnfin<512><<<1, 512, 0, stream>>>(colsum, colsq, bn1g, bn1b, SC1);

    // ---- fuse2 (writes h2 over dead Yb) + BN2 ----
    hipMemsetAsync(colsum, 0, 1024 * 4, stream);
    k_f2<<<dim3(NN / 128, 2), 256, 0, stream>>>(H1, SC1, Wf2, bf2, h2, colsum, colsq);
    k_bnfin<256><<<1, 256, 0, stream>>>(colsum, colsq, bn2g, bn2b, SC2);

    // ---- heads (abuf/vbuf alias dead col) ----
    k_head<<<NN / 4, 256, 0, stream>>>(h2, SC2, Wa, ba, Wv, bv, abuf, vbuf);
    k_lse_part<<<NN / 512, 512, 0, stream>>>(abuf, lsepart);
    k_lse_comb<<<1, 256, 0, stream>>>(lsepart, lseb);
    hipMemsetAsync(gsum, 0, 1024 * 4, stream);
    k_finish<<<NN / 256, 256, 0, stream>>>(abuf, vbuf, batch, lseb, out, gsum, gcnt);
    k_val<<<NG / 256, 256, 0, stream>>>(gsum, gcnt, out + NN);
}

// Round 8
// 1034.386 us; speedup vs baseline: 8.2781x; 2.3442x over previous
//
#include <hip/hip_runtime.h>
#include <hip/hip_bf16.h>

#define NN 115200      // nodes
#define NE 921600      // edges
#define NG 512         // graphs
#define EPSV 1e-5f

typedef unsigned short u16;
struct __align__(8) US4 { u16 x, y, z, w; };
typedef __attribute__((ext_vector_type(8))) short bf16x8;   // 8 bf16 (4 VGPRs)
typedef __attribute__((ext_vector_type(4))) float f32x4;    // MFMA accumulator

static __device__ __forceinline__ float bf(u16 u) {
    return __uint_as_float(((unsigned)u) << 16);
}
static __device__ __forceinline__ u16 fb(float f) {
    unsigned u = __float_as_uint(f);
    return (u16)((u + 0x7FFFu + ((u >> 16) & 1u)) >> 16);   // RNE
}
static __device__ __forceinline__ unsigned pk(float a, float b) {
    return (unsigned)fb(a) | ((unsigned)fb(b) << 16);
}

// ================= CSR build (dst-sorted) =================
__global__ void k_hist(const int* __restrict__ ei, int* __restrict__ cnt) {
    const int e = blockIdx.x * 256 + threadIdx.x;
    atomicAdd(&cnt[ei[NE + e]], 1);
}

__global__ void k_scan1(const int* __restrict__ cnt, int* __restrict__ rowptr,
                        int* __restrict__ psum) {
    __shared__ int sh[256];
    const int t = threadIdx.x, i = blockIdx.x * 256 + t;
    const int v = cnt[i];
    sh[t] = v; __syncthreads();
    for (int o = 1; o < 256; o <<= 1) {
        const int tv = (t >= o) ? sh[t - o] : 0;
        __syncthreads();
        sh[t] += tv;
        __syncthreads();
    }
    rowptr[i] = sh[t] - v;
    if (t == 255) psum[blockIdx.x] = sh[255];
}

__global__ void k_scan2(const int* __restrict__ psum, int* __restrict__ poff) {
    __shared__ int sh[512];
    const int t = threadIdx.x;
    const int v = (t < 450) ? psum[t] : 0;
    sh[t] = v; __syncthreads();
    for (int o = 1; o < 512; o <<= 1) {
        const int tv = (t >= o) ? sh[t - o] : 0;
        __syncthreads();
        sh[t] += tv;
        __syncthreads();
    }
    if (t < 450) poff[t] = sh[t] - v;
}

__global__ void k_scan3(int* __restrict__ rowptr, const int* __restrict__ poff) {
    const int i = blockIdx.x * 256 + threadIdx.x;
    rowptr[i] += poff[blockIdx.x];
    if (i == 0) rowptr[NN] = NE;
}

__global__ void k_fill(const int* __restrict__ ei, const int* __restrict__ rowptr,
                       int* __restrict__ cur, int* __restrict__ col) {
    const int e = blockIdx.x * 256 + threadIdx.x;
    const int d = ei[NE + e];
    const int p = rowptr[d] + atomicAdd(&cur[d], 1);
    col[p] = ei[e];
}

// ---------- weight transpose + bf16 convert: BT[n*K+k] = bf16(W[k*N+n]) ----------
__global__ void k_tr(const float* __restrict__ src, u16* __restrict__ dst,
                     int K, int N, int total) {
    const int o = blockIdx.x * 256 + threadIdx.x;
    if (o < total) {
        const int n = o / K, k = o - n * K;
        dst[o] = fb(src[(size_t)k * N + n]);
    }
}

// ---------- W1/b1 closed-form LN stats + per-feature vectors ----------
__global__ void k_prep(const float* __restrict__ W1, const float* __restrict__ b1,
                       const float* __restrict__ lng, const float* __restrict__ lnb,
                       float* __restrict__ Wg, float* __restrict__ Bg,
                       float* __restrict__ Bt, float* __restrict__ stat) {
    const int j = threadIdx.x;
    const float w = W1[j], b = b1[j];
    __shared__ float r1[256], r2[256], r3[256];
    r1[j] = w; r2[j] = b; __syncthreads();
    for (int o = 128; o > 0; o >>= 1) {
        if (j < o) { r1[j] += r1[j + o]; r2[j] += r2[j + o]; }
        __syncthreads();
    }
    const float mW = r1[0] * (1.f / 256.f), mB = r2[0] * (1.f / 256.f);
    __syncthreads();
    const float dw = w - mW, db = b - mB;
    r1[j] = dw * dw; r2[j] = db * db; r3[j] = dw * db; __syncthreads();
    for (int o = 128; o > 0; o >>= 1) {
        if (j < o) { r1[j] += r1[j + o]; r2[j] += r2[j + o]; r3[j] += r3[j + o]; }
        __syncthreads();
    }
    if (j == 0) { stat[0] = r1[0] * (1.f / 256.f); stat[1] = r3[0] * (1.f / 256.f);
                  stat[2] = r2[0] * (1.f / 256.f); }
    const float gj = lng[j];
    Wg[j] = dw * gj; Bg[j] = db * gj; Bt[j] = lnb[j];
}

// ---------- per-node s0 (CSR gather) + u,w scalars ----------
__global__ void k_s0uw(const float* __restrict__ vert, const int* __restrict__ rowptr,
                       const int* __restrict__ col, const float* __restrict__ stat,
                       float2* __restrict__ UW) {
    const int r = blockIdx.x * 256 + threadIdx.x;
    float s0 = vert[r];
    const int b = rowptr[r], e = rowptr[r + 1];
    for (int k = b; k < e; k++) s0 += vert[col[k]];
    const float var = s0 * s0 * stat[0] + 2.f * s0 * stat[1] + stat[2];
    const float rs = rsqrtf(var + EPSV);
    UW[r] = make_float2(s0 * rs, rs);
}

// ---------- layer-2 aggregation (CSR gather, X on the fly) ----------
__global__ void k_aggX_csr(const int* __restrict__ rowptr, const int* __restrict__ col,
                           const float2* __restrict__ UW, const float* __restrict__ Wg,
                           const float* __restrict__ Bg, const float* __restrict__ Bt,
                           float* __restrict__ S) {
    __shared__ float sWg[256], sBg[256], sBt[256];
    const int tid = threadIdx.x;
    sWg[tid] = Wg[tid]; sBg[tid] = Bg[tid]; sBt[tid] = Bt[tid];
    __syncthreads();
    const int d = blockIdx.x * 4 + (tid >> 6);
    const int j = (tid & 63) * 4;
    const float w0 = sWg[j + 0], w1 = sWg[j + 1], w2 = sWg[j + 2], w3 = sWg[j + 3];
    const float g0 = sBg[j + 0], g1 = sBg[j + 1], g2 = sBg[j + 2], g3 = sBg[j + 3];
    const float t0 = sBt[j + 0], t1 = sBt[j + 1], t2 = sBt[j + 2], t3 = sBt[j + 3];
    float a0 = 0.f, a1 = 0.f, a2 = 0.f, a3 = 0.f;
    const int b = rowptr[d], e = rowptr[d + 1];
    for (int k = b; k < e; k++) {
        const float2 uw = UW[col[k]];
        a0 += fmaxf(uw.x * w0 + uw.y * g0 + t0, 0.f);
        a1 += fmaxf(uw.x * w1 + uw.y * g1 + t1, 0.f);
        a2 += fmaxf(uw.x * w2 + uw.y * g2 + t2, 0.f);
        a3 += fmaxf(uw.x * w3 + uw.y * g3 + t3, 0.f);
    }
    *(float4*)(S + (size_t)d * 256 + j) = make_float4(a0, a1, a2, a3);
}

// ---------- layer-3 aggregation (CSR gather of bf16 Y rows) ----------
__global__ void k_aggY_csr(const int* __restrict__ rowptr, const int* __restrict__ col,
                           const u16* __restrict__ Y, float* __restrict__ S) {
    const int tid = threadIdx.x;
    const int d = blockIdx.x * 4 + (tid >> 6);
    const int j = (tid & 63) * 4;
    float a0 = 0.f, a1 = 0.f, a2 = 0.f, a3 = 0.f;
    const int b = rowptr[d], e = rowptr[d + 1];
    for (int k = b; k < e; k++) {
        const US4 u = *(const US4*)(Y + (size_t)col[k] * 256 + j);
        a0 += bf(u.x); a1 += bf(u.y); a2 += bf(u.z); a3 += bf(u.w);
    }
    *(float4*)(S + (size_t)d * 256 + j) = make_float4(a0, a1, a2, a3);
}

// =======================================================================
// MFMA GEMM + fused LayerNorm (layers 2/3): OUT = relu(LN((A+S)@W + bias))
// tile 64 rows x 256 cols (full row), 256 threads = 4 waves (2m x 2n)
// A staged bf16 into LDS [64][40]; B = pre-transposed bf16 W^T [256][256]
// =======================================================================
template<int SRC>   // 0: A = X on the fly; 1: A = bf16 Ab
__global__ __launch_bounds__(256) void mf_gemm_ln(
    const float2* __restrict__ UW, const float* __restrict__ Wg,
    const float* __restrict__ Bg, const float* __restrict__ Bt,
    const u16* __restrict__ Ab, const float* __restrict__ S,
    const u16* __restrict__ BT, const float* __restrict__ bias,
    const float* __restrict__ g, const float* __restrict__ b,
    u16* __restrict__ OUT) {
    __shared__ u16 Abuf[64 * 40];     // 5120 B
    __shared__ u16 Bbuf[256 * 40];    // 20480 B
    __shared__ float sW[SRC == 0 ? 768 : 1];
    __shared__ float mu_s[64], rs_s[64];
    const int tid = threadIdx.x;
    if (SRC == 0) { sW[tid] = Wg[tid]; sW[256 + tid] = Bg[tid]; sW[512 + tid] = Bt[tid]; __syncthreads(); }
    const int brow = blockIdx.x * 64;
    const int w = tid >> 6, wm = w >> 1, wn = w & 1, l = tid & 63, lr = l & 15, lg = l >> 4;
    const int ra = tid >> 2, qa = tid & 3;
    const f32x4 zero = {0.f, 0.f, 0.f, 0.f};
    f32x4 acc[2][8];
    #pragma unroll
    for (int i = 0; i < 2; i++)
        #pragma unroll
        for (int j = 0; j < 8; j++) acc[i][j] = zero;
    for (int k0 = 0; k0 < 256; k0 += 32) {
        {   // stage A: row ra (0..63), k-octet qa
            const int kb = k0 + qa * 8;
            const float4 s0 = *(const float4*)&S[(size_t)(brow + ra) * 256 + kb];
            const float4 s1 = *(const float4*)&S[(size_t)(brow + ra) * 256 + kb + 4];
            float v[8];
            if (SRC == 0) {
                const float2 uw = UW[brow + ra];
                #pragma unroll
                for (int j = 0; j < 8; j++)
                    v[j] = fmaxf(uw.x * sW[kb + j] + uw.y * sW[256 + kb + j] + sW[512 + kb + j], 0.f);
            } else {
                const uint4 y = *(const uint4*)(Ab + (size_t)(brow + ra) * 256 + kb);
                const u16* yp = (const u16*)&y;
                #pragma unroll
                for (int j = 0; j < 8; j++) v[j] = bf(yp[j]);
            }
            v[0] += s0.x; v[1] += s0.y; v[2] += s0.z; v[3] += s0.w;
            v[4] += s1.x; v[5] += s1.y; v[6] += s1.z; v[7] += s1.w;
            *(uint4*)&Abuf[ra * 40 + qa * 8] =
                make_uint4(pk(v[0], v[1]), pk(v[2], v[3]), pk(v[4], v[5]), pk(v[6], v[7]));
        }
        {   // stage B: col tid (0..255), 32 k
            const u16* src = BT + (size_t)tid * 256 + k0;
            *(uint4*)&Bbuf[tid * 40 + 0]  = *(const uint4*)(src + 0);
            *(uint4*)&Bbuf[tid * 40 + 8]  = *(const uint4*)(src + 8);
            *(uint4*)&Bbuf[tid * 40 + 16] = *(const uint4*)(src + 16);
            *(uint4*)&Bbuf[tid * 40 + 24] = *(const uint4*)(src + 24);
        }
        __syncthreads();
        bf16x8 av[2], bv[8];
        #pragma unroll
        for (int mf = 0; mf < 2; mf++)
            av[mf] = *(const bf16x8*)&Abuf[(wm * 32 + mf * 16 + lr) * 40 + lg * 8];
        #pragma unroll
        for (int nf = 0; nf < 8; nf++)
            bv[nf] = *(const bf16x8*)&Bbuf[(wn * 128 + nf * 16 + lr) * 40 + lg * 8];
        #pragma unroll
        for (int mf = 0; mf < 2; mf++)
            #pragma unroll
            for (int nf = 0; nf < 8; nf++)
                acc[mf][nf] = __builtin_amdgcn_mfma_f32_16x16x32_bf16(av[mf], bv[nf], acc[mf][nf], 0, 0, 0);
        __syncthreads();
    }
    // ---- fused LayerNorm epilogue ----
    float bb[8], gg[8], be[8];
    int cg[8];
    #pragma unroll
    for (int nf = 0; nf < 8; nf++) {
        cg[nf] = wn * 128 + nf * 16 + lr;
        bb[nf] = bias[cg[nf]]; gg[nf] = g[cg[nf]]; be[nf] = b[cg[nf]];
    }
    float* R = (float*)Bbuf;   // [64][33]
    #pragma unroll
    for (int mf = 0; mf < 2; mf++)
        #pragma unroll
        for (int rg = 0; rg < 4; rg++) {
            const int mloc = wm * 32 + mf * 16 + lg * 4 + rg;
            float s = 0.f;
            #pragma unroll
            for (int nf = 0; nf < 8; nf++) s += acc[mf][nf][rg] + bb[nf];
            R[mloc * 33 + wn * 16 + lr] = s;
        }
    __syncthreads();
    if (tid < 64) {
        float s = 0.f;
        for (int t = 0; t < 32; t++) s += R[tid * 33 + t];
        mu_s[tid] = s * (1.f / 256.f);
    }
    __syncthreads();
    #pragma unroll
    for (int mf = 0; mf < 2; mf++)
        #pragma unroll
        for (int rg = 0; rg < 4; rg++) {
            const int mloc = wm * 32 + mf * 16 + lg * 4 + rg;
            const float mu = mu_s[mloc];
            float s = 0.f;
            #pragma unroll
            for (int nf = 0; nf < 8; nf++) {
                const float d = acc[mf][nf][rg] + bb[nf] - mu;
                s += d * d;
            }
            R[mloc * 33 + wn * 16 + lr] = s;
        }
    __syncthreads();
    if (tid < 64) {
        float s = 0.f;
        for (int t = 0; t < 32; t++) s += R[tid * 33 + t];
        rs_s[tid] = rsqrtf(s * (1.f / 256.f) + EPSV);
    }
    __syncthreads();
    #pragma unroll
    for (int mf = 0; mf < 2; mf++)
        #pragma unroll
        for (int rg = 0; rg < 4; rg++) {
            const int mloc = wm * 32 + mf * 16 + lg * 4 + rg;
            const int row = brow + mloc;
            const float mu = mu_s[mloc], rs = rs_s[mloc];
            #pragma unroll
            for (int nf = 0; nf < 8; nf++) {
                const float val = (acc[mf][nf][rg] + bb[nf] - mu) * rs * gg[nf] + be[nf];
                OUT[(size_t)row * 256 + cg[nf]] = fb(fmaxf(val, 0.f));
            }
        }
}

// =======================================================================
// MFMA GEMM (f1 / f2): 128x128 tile, 256 threads = 4 waves (2m x 2n)
// MODE 1: f1  H1 = [vert|X|Y|Z] @ Wf1 + bf1  (K=768, N=512) + BN1 stats
// MODE 2: f2  h2 = relu(BN1(H1)) @ Wf2 + bf2 (K=512, N=256) + BN2 stats
// =======================================================================
template<int MODE>
__global__ __launch_bounds__(256) void mf_gemm(
    const float2* __restrict__ UW, const float* __restrict__ Wg,
    const float* __restrict__ Bg, const float* __restrict__ Bt,
    const u16* __restrict__ Yb, const u16* __restrict__ Zb,
    const u16* __restrict__ H1in, const float2* __restrict__ SC1,
    const u16* __restrict__ BT, const float* __restrict__ bias,
    const float* __restrict__ vert, const float* __restrict__ w0f,
    u16* __restrict__ OUT, float* __restrict__ colsum, float* __restrict__ colsq) {
    constexpr int K  = (MODE == 1) ? 768 : 512;
    constexpr int NC = (MODE == 1) ? 512 : 256;
    __shared__ u16 Abuf[128 * 40];    // 10240 B
    __shared__ u16 Bbuf[128 * 40];    // 10240 B
    __shared__ float sW[MODE == 1 ? 768 : 1];
    __shared__ float2 sSC[MODE == 2 ? 512 : 1];
    const int tid = threadIdx.x;
    if (MODE == 1) { sW[tid] = Wg[tid]; sW[256 + tid] = Bg[tid]; sW[512 + tid] = Bt[tid]; }
    if (MODE == 2) { sSC[tid] = SC1[tid]; sSC[tid + 256] = SC1[tid + 256]; }
    __syncthreads();
    const int brow = blockIdx.x * 128, bcol = blockIdx.y * 128;
    const int w = tid >> 6, wm = w >> 1, wn = w & 1, l = tid & 63, lr = l & 15, lg = l >> 4;
    const int rs_ = tid >> 1, hs = tid & 1;
    const f32x4 zero = {0.f, 0.f, 0.f, 0.f};
    f32x4 acc[4][4];
    #pragma unroll
    for (int i = 0; i < 4; i++)
        #pragma unroll
        for (int j = 0; j < 4; j++) acc[i][j] = zero;
    for (int k0 = 0; k0 < K; k0 += 32) {
        uint4 p0, p1;
        // ---- stage A: row rs_ (0..127), 16 bf16 at k-half hs ----
        if (MODE == 1) {
            if (k0 < 256) {
                const float2 uw = UW[brow + rs_];
                const int kb = k0 + hs * 16;
                float x[16];
                #pragma unroll
                for (int j = 0; j < 16; j++)
                    x[j] = fmaxf(uw.x * sW[kb + j] + uw.y * sW[256 + kb + j] + sW[512 + kb + j], 0.f);
                p0 = make_uint4(pk(x[0], x[1]), pk(x[2], x[3]), pk(x[4], x[5]), pk(x[6], x[7]));
                p1 = make_uint4(pk(x[8], x[9]), pk(x[10], x[11]), pk(x[12], x[13]), pk(x[14], x[15]));
            } else {
                const u16* Asrc = (k0 < 512) ? Yb : Zb;
                const int kb = (k0 & 255) + hs * 16;
                const u16* src = Asrc + (size_t)(brow + rs_) * 256 + kb;
                p0 = *(const uint4*)src; p1 = *(const uint4*)(src + 8);
            }
        } else {
            const int kb = k0 + hs * 16;
            const u16* src = H1in + (size_t)(brow + rs_) * 512 + kb;
            const uint4 q0 = *(const uint4*)src, q1 = *(const uint4*)(src + 8);
            const u16* q0p = (const u16*)&q0;
            const u16* q1p = (const u16*)&q1;
            float x[16];
            #pragma unroll
            for (int j = 0; j < 8; j++) {
                const float2 sc = sSC[kb + j];
                x[j] = fmaxf(bf(q0p[j]) * sc.x + sc.y, 0.f);
            }
            #pragma unroll
            for (int j = 0; j < 8; j++) {
                const float2 sc = sSC[kb + 8 + j];
                x[8 + j] = fmaxf(bf(q1p[j]) * sc.x + sc.y, 0.f);
            }
            p0 = make_uint4(pk(x[0], x[1]), pk(x[2], x[3]), pk(x[4], x[5]), pk(x[6], x[7]));
            p1 = make_uint4(pk(x[8], x[9]), pk(x[10], x[11]), pk(x[12], x[13]), pk(x[14], x[15]));
        }
        *(uint4*)&Abuf[rs_ * 40 + hs * 16 + 0] = p0;
        *(uint4*)&Abuf[rs_ * 40 + hs * 16 + 8] = p1;
        // ---- stage B: col rs_ (0..127) from BT[N][K] ----
        {
            const u16* src = BT + (size_t)(bcol + rs_) * K + k0 + hs * 16;
            *(uint4*)&Bbuf[rs_ * 40 + hs * 16 + 0] = *(const uint4*)src;
            *(uint4*)&Bbuf[rs_ * 40 + hs * 16 + 8] = *(const uint4*)(src + 8);
        }
        __syncthreads();
        bf16x8 av[4], bv[4];
        #pragma unroll
        for (int mf = 0; mf < 4; mf++)
            av[mf] = *(const bf16x8*)&Abuf[(wm * 64 + mf * 16 + lr) * 40 + lg * 8];
        #pragma unroll
        for (int nf = 0; nf < 4; nf++)
            bv[nf] = *(const bf16x8*)&Bbuf[(wn * 64 + nf * 16 + lr) * 40 + lg * 8];
        #pragma unroll
        for (int mf = 0; mf < 4; mf++)
            #pragma unroll
            for (int nf = 0; nf < 4; nf++)
                acc[mf][nf] = __builtin_amdgcn_mfma_f32_16x16x32_bf16(av[mf], bv[nf], acc[mf][nf], 0, 0, 0);
        __syncthreads();
    }
    // ---- epilogue: bias (+vert*w0), bf16 store, BN column stats ----
    float bb[4], w0v[4];
    int cg[4];
    #pragma unroll
    for (int nf = 0; nf < 4; nf++) {
        cg[nf] = bcol + wn * 64 + nf * 16 + lr;
        bb[nf] = bias[cg[nf]];
        if (MODE == 1) w0v[nf] = w0f[cg[nf]];
    }
    float2 ca[4];
    #pragma unroll
    for (int nf = 0; nf < 4; nf++) ca[nf] = make_float2(0.f, 0.f);
    #pragma unroll
    for (int mf = 0; mf < 4; mf++)
        #pragma unroll
        for (int rg = 0; rg < 4; rg++) {
            const int row = brow + wm * 64 + mf * 16 + lg * 4 + rg;
            float vs = 0.f;
            if (MODE == 1) vs = vert[row];
            #pragma unroll
            for (int nf = 0; nf < 4; nf++) {
                float v = acc[mf][nf][rg] + bb[nf];
                if (MODE == 1) v += vs * w0v[nf];
                OUT[(size_t)row * NC + cg[nf]] = fb(v);
                ca[nf].x += v; ca[nf].y += v * v;
            }
        }
    __syncthreads();
    float2* P = (float2*)Abuf;   // [128][8]
    #pragma unroll
    for (int nf = 0; nf < 4; nf++)
        P[(wn * 64 + nf * 16 + lr) * 8 + wm * 4 + lg] = ca[nf];
    __syncthreads();
    if (tid < 128) {
        float s = 0.f, q = 0.f;
        #pragma unroll
        for (int t = 0; t < 8; t++) { const float2 pv = P[tid * 8 + t]; s += pv.x; q += pv.y; }
        atomicAdd(&colsum[bcol + tid], s);
        atomicAdd(&colsq[bcol + tid], q);
    }
}

// ---------- finalize BN: SC[c] = {rs*g, beta - mu*rs*g} ----------
template<int C>
__global__ void k_bnfin(const float* __restrict__ colsum, const float* __restrict__ colsq,
                        const float* __restrict__ g, const float* __restrict__ b,
                        float2* __restrict__ SC) {
    const int c = threadIdx.x;
    const float mu = colsum[c] * (1.f / (float)NN);
    const float var = colsq[c] * (1.f / (float)NN) - mu * mu;
    const float rs = rsqrtf(fmaxf(var, 0.f) + EPSV);
    const float sc = rs * g[c];
    SC[c] = make_float2(sc, b[c] - mu * sc);
}

// ---------- heads: apply BN2+relu on load, dot with Wa / Wv ----------
__global__ void k_head(const u16* __restrict__ h2, const float2* __restrict__ SC2,
                       const float* __restrict__ Wa, const float* __restrict__ ba,
                       const float* __restrict__ Wv, const float* __restrict__ bv,
                       float* __restrict__ abuf, float* __restrict__ vbuf) {
    const int node = blockIdx.x * 4 + (threadIdx.x >> 6);
    const int lane = threadIdx.x & 63;
    const US4 u = *(const US4*)(h2 + (size_t)node * 256 + lane * 4);
    const float4 wa = *(const float4*)(Wa + lane * 4);
    const float4 wv = *(const float4*)(Wv + lane * 4);
    const float2 s0 = SC2[lane * 4 + 0], s1 = SC2[lane * 4 + 1];
    const float2 s2 = SC2[lane * 4 + 2], s3 = SC2[lane * 4 + 3];
    const float h0 = fmaxf(bf(u.x) * s0.x + s0.y, 0.f);
    const float h1 = fmaxf(bf(u.y) * s1.x + s1.y, 0.f);
    const float h2v = fmaxf(bf(u.z) * s2.x + s2.y, 0.f);
    const float h3 = fmaxf(bf(u.w) * s3.x + s3.y, 0.f);
    float da = h0 * wa.x + h1 * wa.y + h2v * wa.z + h3 * wa.w;
    float dv = h0 * wv.x + h1 * wv.y + h2v * wv.z + h3 * wv.w;
    for (int o = 32; o > 0; o >>= 1) {
        da += __shfl_down(da, o);
        dv += __shfl_down(dv, o);
    }
    if (lane == 0) {
        abuf[node] = da + ba[0];
        vbuf[node] = dv + bv[0];
    }
}

// ---------- logsumexp: parallel partials + combine ----------
__global__ void k_lse_part(const float* __restrict__ a, float2* __restrict__ part) {
    __shared__ float red[512];
    const int t = threadIdx.x;
    const float v = a[blockIdx.x * 512 + t];
    red[t] = v; __syncthreads();
    for (int o = 256; o > 0; o >>= 1) { if (t < o) red[t] = fmaxf(red[t], red[t + o]); __syncthreads(); }
    const float m = red[0];
    __syncthreads();
    red[t] = expf(v - m); __syncthreads();
    for (int o = 256; o > 0; o >>= 1) { if (t < o) red[t] += red[t + o]; __syncthreads(); }
    if (t == 0) part[blockIdx.x] = make_float2(m, red[0]);
}

__global__ void k_lse_comb(const float2* __restrict__ part, float* __restrict__ lseb) {
    __shared__ float rm[256], rsum[256];
    const int t = threadIdx.x;
    const float2 p = (t < 225) ? part[t] : make_float2(-3.4e38f, 0.f);
    rm[t] = p.x; __syncthreads();
    for (int o = 128; o > 0; o >>= 1) { if (t < o) rm[t] = fmaxf(rm[t], rm[t + o]); __syncthreads(); }
    const float M = rm[0];
    __syncthreads();
    rsum[t] = p.y * expf(p.x - M); __syncthreads();
    for (int o = 128; o > 0; o >>= 1) { if (t < o) rsum[t] += rsum[t + o]; __syncthreads(); }
    if (t == 0) lseb[0] = M + logf(rsum[0]);
}

// ---------- act output + graph segment sums ----------
__global__ void k_finish(const float* __restrict__ abuf, const float* __restrict__ vbuf,
                         const int* __restrict__ batch, const float* __restrict__ lseb,
                         float* __restrict__ out_act, float* __restrict__ gsum,
                         float* __restrict__ gcnt) {
    const int i = blockIdx.x * 256 + threadIdx.x;
    out_act[i] = abuf[i] - lseb[0];
    atomicAdd(&gsum[batch[i]], vbuf[i]);
    atomicAdd(&gcnt[batch[i]], 1.f);
}

__global__ void k_val(const float* __restrict__ gsum, const float* __restrict__ gcnt,
                      float* __restrict__ out_val) {
    const int g = blockIdx.x * 256 + threadIdx.x;
    out_val[g] = tanhf(gsum[g] / fmaxf(gcnt[g], 1.f));
}

extern "C" void kernel_launch(void* const* d_in, const int* in_sizes, int n_in,
                              void* d_out, int out_size, void* d_ws, size_t ws_size,
                              hipStream_t stream) {
    const float* vert = (const float*)d_in[0];
    const int* ei   = (const int*)d_in[1];
    const int* batch= (const int*)d_in[2];
    const float* W1  = (const float*)d_in[3];
    const float* b1  = (const float*)d_in[4];
    const float* W2  = (const float*)d_in[5];
    const float* b2  = (const float*)d_in[6];
    const float* W3  = (const float*)d_in[7];
    const float* b3  = (const float*)d_in[8];
    const float* lng = (const float*)d_in[9];
    const float* lnb = (const float*)d_in[10];
    const float* Wf1 = (const float*)d_in[11];
    const float* bf1 = (const float*)d_in[12];
    const float* Wf2 = (const float*)d_in[13];
    const float* bf2 = (const float*)d_in[14];
    const float* bn1g= (const float*)d_in[15];
    const float* bn1b= (const float*)d_in[16];
    const float* bn2g= (const float*)d_in[17];
    const float* bn2b= (const float*)d_in[18];
    const float* Wa  = (const float*)d_in[19];
    const float* ba  = (const float*)d_in[20];
    const float* Wv  = (const float*)d_in[21];
    const float* bv  = (const float*)d_in[22];

    // ---- workspace layout (~243 MB) ----
    const size_t NHB = (size_t)NN * 1024;
    float* S  = (float*)d_ws;
    u16*   H1 = (u16*)d_ws;
    u16*   Yb = (u16*)((char*)d_ws + NHB);
    u16*   Zb = Yb + (size_t)NN * 256;
    u16*   h2 = Yb;
    float* tail = (float*)((char*)d_ws + 2 * NHB);
    float2* UW    = (float2*)tail;            // NN float2
    float* Wg     = tail + 2 * (size_t)NN;    // 256
    float* Bg     = Wg + 256;
    float* Bt     = Bg + 256;
    float* stat   = Bt + 256;                 // 4
    float* colsum = stat + 4;                 // 512
    float* colsq  = colsum + 512;             // 512
    float2* SC1   = (float2*)(colsq + 512);   // 512 float2
    float2* SC2   = SC1 + 512;                // 256 float2
    float* gsum   = (float*)(SC2 + 256);      // 512
    float* gcnt   = gsum + 512;               // 512
    float* lseb   = gcnt + 512;               // 1 (+pad)
    float2* lsepart = (float2*)(lseb + 4);    // 225 float2
    int*   cnt    = (int*)(lseb + 4 + 456);   // NN
    int*   rowptr = cnt + NN;                 // NN+1 (+pad)
    int*   psum   = rowptr + NN + 4;          // 512
    int*   poff   = psum + 512;               // 512
    int*   col    = poff + 512;               // NE
    float* abuf   = (float*)col;              // aliases col (dead by k_head)
    float* vbuf   = abuf + NN;
    // bf16 transposed weights after col (256B-aligned)
    size_t btoff = ((size_t)((char*)(col + NE) - (char*)d_ws) + 255) & ~(size_t)255;
    u16* BT2  = (u16*)((char*)d_ws + btoff);  // [256][256]
    u16* BT3  = BT2 + 65536;                  // [256][256]
    u16* BTf1 = BT3 + 65536;                  // [512][768]
    u16* BTf2 = BTf1 + 393216;                // [256][512]

    float* out = (float*)d_out;

    // ---- CSR build (dst-sorted) ----
    hipMemsetAsync(cnt, 0, (size_t)NN * 4, stream);
    k_hist<<<NE / 256, 256, 0, stream>>>(ei, cnt);
    k_scan1<<<NN / 256, 256, 0, stream>>>(cnt, rowptr, psum);
    k_scan2<<<1, 512, 0, stream>>>(psum, poff);
    k_scan3<<<NN / 256, 256, 0, stream>>>(rowptr, poff);
    hipMemsetAsync(cnt, 0, (size_t)NN * 4, stream);
    k_fill<<<NE / 256, 256, 0, stream>>>(ei, rowptr, cnt, col);

    // ---- weight transposes (fp32 -> bf16 W^T) ----
    k_tr<<<65536 / 256, 256, 0, stream>>>(W2, BT2, 256, 256, 65536);
    k_tr<<<65536 / 256, 256, 0, stream>>>(W3, BT3, 256, 256, 65536);
    k_tr<<<393216 / 256, 256, 0, stream>>>(Wf1 + 512, BTf1, 768, 512, 393216);
    k_tr<<<131072 / 256, 256, 0, stream>>>(Wf2, BTf2, 512, 256, 131072);

    // ---- layer 1 (closed-form X) ----
    k_prep<<<1, 256, 0, stream>>>(W1, b1, lng, lnb, Wg, Bg, Bt, stat);
    k_s0uw<<<NN / 256, 256, 0, stream>>>(vert, rowptr, col, stat, UW);

    // ---- layer 2 ----
    k_aggX_csr<<<NN / 4, 256, 0, stream>>>(rowptr, col, UW, Wg, Bg, Bt, S);
    mf_gemm_ln<0><<<NN / 64, 256, 0, stream>>>(UW, Wg, Bg, Bt, nullptr, S, BT2,
                                               b2, lng, lnb, Yb);

    // ---- layer 3 ----
    k_aggY_csr<<<NN / 4, 256, 0, stream>>>(rowptr, col, Yb, S);
    mf_gemm_ln<1><<<NN / 64, 256, 0, stream>>>(nullptr, nullptr, nullptr, nullptr, Yb, S,
                                               BT3, b3, lng, lnb, Zb);

    // ---- fuse1 (H1 over dead S) + BN1 ----
    hipMemsetAsync(colsum, 0, 1024 * 4, stream);
    mf_gemm<1><<<dim3(NN / 128, 4), 256, 0, stream>>>(UW, Wg, Bg, Bt, Yb, Zb,
                                                      nullptr, nullptr, BTf1, bf1,
                                                      vert, Wf1, H1, colsum, colsq);
    k_bnfin<512><<<1, 512, 0, stream>>>(colsum, colsq, bn1g, bn1b, SC1);

    // ---- fuse2 (h2 over dead Yb) + BN2 ----
    hipMemsetAsync(colsum, 0, 1024 * 4, stream);
    mf_gemm<2><<<dim3(NN / 128, 2), 256, 0, stream>>>(nullptr, nullptr, nullptr, nullptr,
                                                      nullptr, nullptr, H1, SC1, BTf2, bf2,
                                                      nullptr, nullptr, h2, colsum, colsq);
    k_bnfin<256><<<1, 256, 0, stream>>>(colsum, colsq, bn2g, bn2b, SC2);

    // ---- heads ----
    k_head<<<NN / 4, 256, 0, stream>>>(h2, SC2, Wa, ba, Wv, bv, abuf, vbuf);
    k_lse_part<<<NN / 512, 512, 0, stream>>>(abuf, lsepart);
    k_lse_comb<<<1, 256, 0, stream>>>(lsepart, lseb);
    hipMemsetAsync(gsum, 0, 1024 * 4, stream);
    k_finish<<<NN / 256, 256, 0, stream>>>(abuf, vbuf, batch, lseb, out, gsum, gcnt);
    k_val<<<NG / 256, 256, 0, stream>>>(gsum, gcnt, out + NN);
}